// Round 14
// baseline (289.011 us; speedup 1.0000x reference)
//
#include <hip/hip_runtime.h>
#include <stdint.h>

#define N_DET 20000
#define N_CLS 80
#define NELEM (N_DET * N_CLS)
#define TOPK  1000
#define CONF  0.05f
#define CANDS 1280
#define SORTN 2048
#define NBLK  40   // blocks for hist/scatter passes

typedef unsigned long long u64;
typedef unsigned int u32;

__device__ inline u64 shfl64(u64 v, int src) {
  int lo = __shfl((int)(u32)v, src, 64);
  int hi = __shfl((int)(v >> 32), src, 64);
  return ((u64)(u32)hi << 32) | (u32)lo;
}

// Exact replication of RN(inter/denom) > 0.5 without fdiv:
// RN(a/b) > 0.5  <=>  a/b > 0.5 + 2^-25 (tie rounds-to-even to 0.5)
//               <=>  a * 2^25 > b * (2^24 + 1), both products exact in f64.
__device__ __forceinline__ bool iou_gt_half(float4 bi, float ai,
                                            float4 bj, float aj) {
  #pragma clang fp contract(off)
  float iw = fmaxf(fminf(bi.z, bj.z) - fmaxf(bi.x, bj.x), 0.0f);
  float ih = fmaxf(fminf(bi.w, bj.w) - fmaxf(bi.y, bj.y), 0.0f);
  float inter = iw * ih;
  float denom = ai + aj - inter + 1e-9f;
  return (double)inter * 33554432.0 > (double)denom * 16777217.0;
}

// ---------------------------------------------------------------------------
// Workspace layout (small part total 1,624,320 B - NO overlaps):
//   T16 @0 (320) | prefA @320 | tgtA @640 | cnt @960
//   top_s @1280 (320000) | top_idx @321280 (320000) | cls_out @641280 (40960)
//   ghistA @682240 (40960) | ghistB @723200 (81920) | cand @805120 (819200)
//   maskG @1624320 (10,240,000)   [only if ws_size >= 11,864,320]
// ---------------------------------------------------------------------------
#define OFF_T16    0
#define OFF_PREFA  320
#define OFF_TGTA   640
#define OFF_CNT    960
#define OFF_TOPS   1280
#define OFF_TOPI   321280
#define OFF_CLSOUT 641280
#define OFF_GHA    682240
#define OFF_GHB    723200
#define OFF_CAND   805120
#define OFF_MASK   1624320
#define MASK_BYTES (80ull * TOPK * 16 * 8)

// ---------------------------------------------------------------------------
// Pass A: level-0 histogram, bins = float-bits >> 23 (clamped to 127).
// ---------------------------------------------------------------------------
__global__ __launch_bounds__(256) void k_histA(
    const float* __restrict__ S, u32* __restrict__ gh) {
  __shared__ u32 h[N_CLS * 129];
  for (int i = threadIdx.x; i < N_CLS * 129; i += 256) h[i] = 0;
  __syncthreads();
  const int per = NELEM / 4 / NBLK;
  const float4* S4 = (const float4*)S;
  const int v0 = blockIdx.x * per;
  for (int v = v0 + threadIdx.x; v < v0 + per; v += 256) {
    float4 f = S4[v];
    int c0 = (v * 4) % N_CLS;
    u32 b0 = __float_as_uint(f.x) >> 23; if (b0 > 127u) b0 = 127u;
    u32 b1 = __float_as_uint(f.y) >> 23; if (b1 > 127u) b1 = 127u;
    u32 b2 = __float_as_uint(f.z) >> 23; if (b2 > 127u) b2 = 127u;
    u32 b3 = __float_as_uint(f.w) >> 23; if (b3 > 127u) b3 = 127u;
    atomicAdd(&h[(c0 + 0) * 129 + b0], 1u);
    atomicAdd(&h[(c0 + 1) * 129 + b1], 1u);
    atomicAdd(&h[(c0 + 2) * 129 + b2], 1u);
    atomicAdd(&h[(c0 + 3) * 129 + b3], 1u);
  }
  __syncthreads();
  for (int i = threadIdx.x; i < N_CLS * 128; i += 256) {
    u32 v = h[(i >> 7) * 129 + (i & 127)];
    if (v) atomicAdd(&gh[i], v);
  }
}

__global__ __launch_bounds__(256) void k_thrA(
    const u32* __restrict__ gh, u32* __restrict__ prefA, u32* __restrict__ tgtA) {
  __shared__ u32 h[N_CLS * 129];
  for (int i = threadIdx.x; i < N_CLS * 128; i += 256)
    h[(i >> 7) * 129 + (i & 127)] = gh[i];
  __syncthreads();
  const int c = threadIdx.x;
  if (c >= N_CLS) return;
  u32 acc = 0;
  for (int b = 127; b >= 0; --b) {
    u32 hv = h[c * 129 + b];
    acc += hv;
    if (acc >= TOPK) { prefA[c] = (u32)b; tgtA[c] = TOPK - (acc - hv); return; }
  }
  prefA[c] = 0; tgtA[c] = TOPK;
}

// ---------------------------------------------------------------------------
// Pass B: level-1 histogram over bits [22:15] for elements in the level-0 bin.
// ---------------------------------------------------------------------------
__global__ __launch_bounds__(256) void k_histB(
    const float* __restrict__ S, const u32* __restrict__ prefA,
    u32* __restrict__ gh) {
  __shared__ u32 h[N_CLS * 257];
  __shared__ u32 pA[N_CLS];
  for (int i = threadIdx.x; i < N_CLS * 257; i += 256) h[i] = 0;
  for (int i = threadIdx.x; i < N_CLS; i += 256) pA[i] = prefA[i];
  __syncthreads();
  const int per = NELEM / 4 / NBLK;
  const float4* S4 = (const float4*)S;
  const int v0 = blockIdx.x * per;
  for (int v = v0 + threadIdx.x; v < v0 + per; v += 256) {
    float4 f = S4[v];
    int c0 = (v * 4) % N_CLS;
    u32 bb[4] = {__float_as_uint(f.x), __float_as_uint(f.y),
                 __float_as_uint(f.z), __float_as_uint(f.w)};
    #pragma unroll
    for (int k = 0; k < 4; ++k) {
      u32 e = bb[k] >> 23; if (e > 127u) e = 127u;
      if (e == pA[c0 + k])
        atomicAdd(&h[(c0 + k) * 257 + ((bb[k] >> 15) & 0xFF)], 1u);
    }
  }
  __syncthreads();
  for (int i = threadIdx.x; i < N_CLS * 256; i += 256) {
    u32 v = h[(i >> 8) * 257 + (i & 255)];
    if (v) atomicAdd(&gh[i], v);
  }
}

__global__ __launch_bounds__(256) void k_thrB(
    const u32* __restrict__ gh, const u32* __restrict__ prefA,
    const u32* __restrict__ tgtA, u32* __restrict__ T16) {
  __shared__ u32 h[N_CLS * 257];
  for (int i = threadIdx.x; i < N_CLS * 256; i += 256)
    h[(i >> 8) * 257 + (i & 255)] = gh[i];
  __syncthreads();
  const int c = threadIdx.x;
  if (c >= N_CLS) return;
  const u32 tgt = tgtA[c];
  u32 acc = 0, B1 = 0;
  for (int b = 255; b >= 0; --b) {
    acc += h[c * 257 + b];
    if (acc >= tgt) { B1 = (u32)b; break; }
  }
  T16[c] = (prefA[c] << 23) | (B1 << 15);
}

// ---------------------------------------------------------------------------
// Scatter, two-phase: LDS per-class count -> ONE global atomicAdd per
// (block,class) -> re-read + place at reserved offsets.
// ---------------------------------------------------------------------------
__global__ __launch_bounds__(256) void k_scatter(
    const float* __restrict__ S, const u32* __restrict__ T16,
    u32* __restrict__ cnt, u64* __restrict__ cand) {
  __shared__ u32 tl[N_CLS];
  __shared__ u32 lcnt[N_CLS];
  __shared__ u32 gbase[N_CLS];
  for (int i = threadIdx.x; i < N_CLS; i += 256) { tl[i] = T16[i]; lcnt[i] = 0; }
  __syncthreads();
  const int per = NELEM / 4 / NBLK;
  const float4* S4 = (const float4*)S;
  const int v0 = blockIdx.x * per;
  for (int v = v0 + threadIdx.x; v < v0 + per; v += 256) {
    float4 f = S4[v];
    const int c0 = (v * 4) % N_CLS;
    u32 bb[4] = {__float_as_uint(f.x), __float_as_uint(f.y),
                 __float_as_uint(f.z), __float_as_uint(f.w)};
    #pragma unroll
    for (int k = 0; k < 4; ++k)
      if (bb[k] >= tl[c0 + k]) atomicAdd(&lcnt[c0 + k], 1u);
  }
  __syncthreads();
  for (int i = threadIdx.x; i < N_CLS; i += 256) {
    u32 n = lcnt[i];
    gbase[i] = n ? atomicAdd(&cnt[i], n) : 0u;
    lcnt[i] = 0;
  }
  __syncthreads();
  for (int v = v0 + threadIdx.x; v < v0 + per; v += 256) {
    float4 f = S4[v];
    const int base = v * 4;
    const int c0 = base % N_CLS;
    const u32 row = (u32)(base / N_CLS);
    u32 bb[4] = {__float_as_uint(f.x), __float_as_uint(f.y),
                 __float_as_uint(f.z), __float_as_uint(f.w)};
    #pragma unroll
    for (int k = 0; k < 4; ++k) {
      if (bb[k] >= tl[c0 + k]) {
        u32 p = gbase[c0 + k] + atomicAdd(&lcnt[c0 + k], 1u);
        if (p < CANDS)
          cand[(size_t)(c0 + k) * CANDS + p] = ((u64)bb[k] << 32) | (u32)(~row);
      }
    }
  }
}

// ---------------------------------------------------------------------------
// Per-class bitonic sort -> top-1000 scores + box indices. 512 threads.
// ---------------------------------------------------------------------------
__global__ __launch_bounds__(512) void k_sort(
    const u64* __restrict__ cand, const u32* __restrict__ cnt,
    float* __restrict__ top_s, u32* __restrict__ top_idx) {
  const int c = blockIdx.x, t = threadIdx.x;
  __shared__ u64 keys[SORTN];
  u32 n = cnt[c]; if (n > CANDS) n = CANDS;
  for (int i = t; i < SORTN; i += 512)
    keys[i] = (i < (int)n) ? cand[(size_t)c * CANDS + i] : 0ull;
  __syncthreads();
  for (int k = 2; k <= SORTN; k <<= 1)
    for (int j = k >> 1; j > 0; j >>= 1) {
      for (int p = t; p < SORTN / 2; p += 512) {
        int i  = ((p & ~(j - 1)) << 1) | (p & (j - 1));
        int ix = i | j;
        bool up = (i & k) == 0;
        u64 a = keys[i], b = keys[ix];
        if (up ? (a < b) : (a > b)) { keys[i] = b; keys[ix] = a; }
      }
      __syncthreads();
    }
  for (int i = t; i < TOPK; i += 512) {
    u64 kk = keys[i];
    u32 idx = ~(u32)kk;
    if (kk == 0ull || idx >= N_DET) idx = 0;
    top_s[c * TOPK + i] = __uint_as_float((u32)(kk >> 32));
    top_idx[c * TOPK + i] = idx;
  }
}

// ---------------------------------------------------------------------------
// PATH P (big ws): mask kernel over the whole machine.
// Grid (80 classes, 25 row-blocks of 40 rows), 256 thr.
// ---------------------------------------------------------------------------
__global__ __launch_bounds__(256) void k_mask(
    const u32* __restrict__ top_idx, const float* __restrict__ boxes,
    u64* __restrict__ maskG) {
  const int c = blockIdx.x;
  const int tid = threadIdx.x, wave = tid >> 6, lane = tid & 63;
  __shared__ float4 sbox[TOPK];
  __shared__ float sarea[TOPK];
  for (int i = tid; i < TOPK; i += 256) {
    u32 idx = top_idx[c * TOPK + i];
    if (idx >= N_DET) idx = 0;
    float4 b = ((const float4*)boxes)[idx];
    sbox[i] = b;
    sarea[i] = (b.z - b.x) * (b.w - b.y);
  }
  __syncthreads();
  float4 cb[16]; float ca[16];
  #pragma unroll
  for (int s = 0; s < 16; ++s) {
    int j = s * 64 + lane;
    cb[s] = (j < TOPK) ? sbox[j] : make_float4(0.f, 0.f, 0.f, 0.f);
    ca[s] = (j < TOPK) ? sarea[j] : 0.f;
  }
  for (int rr = 0; rr < 10; ++rr) {
    const int i = blockIdx.y * 40 + wave * 10 + rr;
    float4 bi = sbox[i];
    float ai = sarea[i];
    const int s0 = i >> 6;
    u64 w = 0;
    #pragma unroll
    for (int s = 0; s < 16; ++s) {
      if (s >= s0) {
        int j = s * 64 + lane;
        bool sup = iou_gt_half(bi, ai, cb[s], ca[s]);
        if (s == s0) sup &= (j > i);
        u64 bal = __ballot(sup);
        if (lane == s) w = bal;
      }
    }
    if (lane < 16) maskG[((size_t)c * TOPK + i) * 16 + lane] = w;
  }
}

// ---------------------------------------------------------------------------
// PATH P: sweep v3 (512 thr): bulk LDS stage + 32-row word-batched resolve.
// ---------------------------------------------------------------------------
__global__ __launch_bounds__(512) void k_sweep(
    const float* __restrict__ top_s, const u64* __restrict__ maskG,
    float* __restrict__ cls_out) {
  const int c = blockIdx.x;
  const int tid = threadIdx.x, wave = tid >> 6, lane = tid & 63;
  __shared__ u64 maskL[TOPK * 16];  // 128000 B

  {
    const uint4* src = (const uint4*)(maskG + (size_t)c * TOPK * 16);
    uint4* dst = (uint4*)maskL;
    for (int i = tid; i < TOPK * 16 / 2; i += 512) dst[i] = src[i];
  }
  __syncthreads();

  if (wave == 0) {
    u64 kw = 0;
    for (int s = 0; s < 16; ++s) {
      int j = s * 64 + lane;
      bool valid = (j < TOPK) && (top_s[c * TOPK + j] > CONF);
      u64 bal = __ballot(valid);
      if (lane == s) kw = bal;
    }
    u32 keep32 = (u32)(shfl64(kw, lane >> 1) >> ((lane & 1) * 32));
    const u32* M32 = (const u32*)maskL;   // row i word w: M32[i*32 + w]
    const int li = lane & 31;

    u32 rcur[32], rnxt[32];
    #pragma unroll
    for (int d = 0; d < 32; ++d)
      rcur[d] = M32[d * 32 + li];

    for (int b = 0; b < 32; ++b) {
      if (b < 31) {
        #pragma unroll
        for (int d = 0; d < 32; ++d) {
          int row = (b + 1) * 32 + d;
          if (row >= TOPK) row = 0;
          rnxt[d] = M32[row * 32 + li];
        }
      }
      u32 w = __builtin_amdgcn_readlane(keep32, b);
      u32 kbits = 0u;
      #pragma unroll
      for (int d = 0; d < 32; ++d) {
        u32 rd = __builtin_amdgcn_readlane(rcur[d], b);
        u32 bit = (w >> d) & 1u;
        w &= ~(rd & (0u - bit));
        kbits |= bit << d;
      }
      u32 sup = 0u;
      #pragma unroll
      for (int d = 0; d < 32; ++d)
        sup |= rcur[d] & (0u - ((kbits >> d) & 1u));
      keep32 &= ~sup;
      #pragma unroll
      for (int d = 0; d < 32; ++d) rcur[d] = rnxt[d];
    }

    int base = 0;
    #pragma unroll
    for (int s = 0; s < 16; ++s) {
      u32 lo = __builtin_amdgcn_readlane(keep32, 2 * s);
      u32 hi = __builtin_amdgcn_readlane(keep32, 2 * s + 1);
      u64 w = ((u64)hi << 32) | lo;
      int pos = base + __popcll(w & ((1ull << lane) - 1ull));
      if (((w >> lane) & 1ull) && pos < 100)
        cls_out[c * 128 + pos] = top_s[c * TOPK + s * 64 + lane];
      base += __popcll(w);
    }
  }
}

// ---------------------------------------------------------------------------
// PATH Q (small ws): fused mask(LDS)+sweep, 16 waves, 1 block/CU.
// ---------------------------------------------------------------------------
__global__ __launch_bounds__(1024) void k_nms(
    const float* __restrict__ top_s, const u32* __restrict__ top_idx,
    const float* __restrict__ boxes, float* __restrict__ cls_out) {
  const int c = blockIdx.x;
  const int tid = threadIdx.x, wave = tid >> 6, lane = tid & 63;
  __shared__ float4 sbox[TOPK];
  __shared__ float sarea[TOPK];
  __shared__ u64 maskL[TOPK * 16];

  for (int i = tid; i < TOPK; i += 1024) {
    u32 idx = top_idx[c * TOPK + i];
    if (idx >= N_DET) idx = 0;
    float4 b = ((const float4*)boxes)[idx];
    sbox[i] = b;
    sarea[i] = (b.z - b.x) * (b.w - b.y);
  }
  __syncthreads();

  float4 cb[16]; float ca[16];
  #pragma unroll
  for (int s = 0; s < 16; ++s) {
    int j = s * 64 + lane;
    cb[s] = (j < TOPK) ? sbox[j] : make_float4(0.f, 0.f, 0.f, 0.f);
    ca[s] = (j < TOPK) ? sarea[j] : 0.f;
  }

  for (int i = wave; i < TOPK; i += 16) {
    float4 bi = sbox[i];
    float ai = sarea[i];
    const int s0 = i >> 6;
    u64 w = 0;
    #pragma unroll
    for (int s = 0; s < 16; ++s) {
      if (s >= s0) {
        int j = s * 64 + lane;
        bool sup = iou_gt_half(bi, ai, cb[s], ca[s]);
        if (s == s0) sup &= (j > i);
        u64 bal = __ballot(sup);
        if (lane == s) w = bal;
      }
    }
    if (lane < 16) maskL[i * 16 + lane] = w;
  }
  __syncthreads();

  if (wave == 0) {
    u64 kw = 0;
    for (int s = 0; s < 16; ++s) {
      int j = s * 64 + lane;
      bool valid = (j < TOPK) && (top_s[c * TOPK + j] > CONF);
      u64 bal = __ballot(valid);
      if (lane == s) kw = bal;
    }
    u32 keep32 = (u32)(shfl64(kw, lane >> 1) >> ((lane & 1) * 32));
    const u32* M32 = (const u32*)maskL;
    const bool ld = lane < 32;
    u32 rbuf[8];
    #pragma unroll
    for (int d = 0; d < 8; ++d)
      rbuf[d] = ld ? M32[d * 32 + lane] : 0u;
    for (int ib = 0; ib < TOPK; ib += 8) {
      #pragma unroll
      for (int d = 0; d < 8; ++d) {
        const int i = ib + d;
        u32 wv = __builtin_amdgcn_readlane(keep32, i >> 5);
        if ((wv >> (i & 31)) & 1u) keep32 &= ~rbuf[d];
        int nx = ib + 8 + d;
        rbuf[d] = (ld && nx < TOPK) ? M32[nx * 32 + lane] : 0u;
      }
    }
    int base = 0;
    #pragma unroll
    for (int s = 0; s < 16; ++s) {
      u32 lo = __builtin_amdgcn_readlane(keep32, 2 * s);
      u32 hi = __builtin_amdgcn_readlane(keep32, 2 * s + 1);
      u64 w = ((u64)hi << 32) | lo;
      int pos = base + __popcll(w & ((1ull << lane) - 1ull));
      if (((w >> lane) & 1ull) && pos < 100)
        cls_out[c * 128 + pos] = top_s[c * TOPK + s * 64 + lane];
      base += __popcll(w);
    }
  }
}

// ---------------------------------------------------------------------------
// Global top-100: SINGLE-WAVE two-level radix select, zero multi-wave
// barriers (R13: 256-thr version spent 47 us in ~40 x 1.2 us barriers).
// Both suffix-scans are two-stage wave-parallel (chunk table -> owner chunk
// re-split across lanes -> serial tail <= 4 bins). Compaction via ballot.
// Fallback (nc>512, adversarial ties): full 8192 single-wave bitonic.
// ---------------------------------------------------------------------------
__global__ __launch_bounds__(64) void k_final(
    const float* __restrict__ cls_out, float* __restrict__ out) {
  __shared__ u32 vals[8000];    // 32000 B
  __shared__ u32 h1[8192];      // 32768 B
  __shared__ u32 h2[16384];     // 65536 B
  __shared__ u32 ls[64];
  __shared__ u32 cands[512];
  __shared__ u32 sC, sAb, sPref, sT2, sThr;
  const int lane = threadIdx.x;

  uint4 z4 = make_uint4(0u, 0u, 0u, 0u);
  for (int i = lane; i < 2048; i += 64) ((uint4*)h1)[i] = z4;
  for (int i = lane; i < 4096; i += 64) ((uint4*)h2)[i] = z4;
  for (int i = lane; i < 128; i += 64) ((uint4*)cands)[i] = z4;
  if (lane == 0) { sC = 0; sAb = 0; sPref = 0; sT2 = 1; sThr = 0; }
  __builtin_amdgcn_wave_barrier();

  // load + level-1 histogram of bits>>17 (zeros land in bin 0)
  for (int i = lane; i < 8000; i += 64) {
    u32 b = __float_as_uint(cls_out[(i / 100) * 128 + (i % 100)]);
    vals[i] = b;
    u32 bin = b >> 17; if (bin > 8191u) bin = 8191u;
    atomicAdd(&h1[bin], 1u);
  }
  __builtin_amdgcn_wave_barrier();

  // ---- level-1 select (target 100): chunks of 128, then 2 bins/lane
  {
    const u32 cb = (u32)lane * 128u;
    u32 lsum = 0;
    for (int k = 0; k < 128; ++k) lsum += h1[cb + k];
    ls[lane] = lsum;
    __builtin_amdgcn_wave_barrier();
    u32 above = 0;
    for (int l2 = lane + 1; l2 < 64; ++l2) above += ls[l2];
    if (above < 100u && above + lsum >= 100u) { sC = (u32)lane; sAb = above; }
    __builtin_amdgcn_wave_barrier();
    const u32 C = sC, Ab = sAb;
    const u32 b2 = C * 128u + (u32)lane * 2u;
    u32 hHi = h1[b2 + 1], hLo = h1[b2];
    u32 ls2 = hHi + hLo;
    __builtin_amdgcn_wave_barrier();
    ls[lane] = ls2;
    __builtin_amdgcn_wave_barrier();
    u32 ab2 = Ab;
    for (int l2 = lane + 1; l2 < 64; ++l2) ab2 += ls[l2];
    if (ab2 < 100u && ab2 + ls2 >= 100u) {
      if (ab2 + hHi >= 100u) { sPref = b2 + 1; sT2 = 100u - ab2; }
      else                   { sPref = b2;     sT2 = 100u - (ab2 + hHi); }
    }
    __builtin_amdgcn_wave_barrier();
  }
  const u32 pref = sPref, rt = sT2;   // residual target in [1,100]

  // ---- level-2 histogram over bits[16:3] for elements in bin pref
  for (int i = lane; i < 8000; i += 64) {
    u32 b = vals[i];
    u32 bin = b >> 17; if (bin > 8191u) bin = 8191u;
    if (bin == pref) atomicAdd(&h2[(b >> 3) & 0x3FFFu], 1u);
  }
  __builtin_amdgcn_wave_barrier();

  // ---- level-2 select (target rt): chunks of 256, then 4 bins/lane
  {
    const u32 cb = (u32)lane * 256u;
    u32 lsum = 0;
    for (int k = 0; k < 256; ++k) lsum += h2[cb + k];
    ls[lane] = lsum;
    __builtin_amdgcn_wave_barrier();
    u32 above = 0;
    for (int l2 = lane + 1; l2 < 64; ++l2) above += ls[l2];
    if (above < rt && above + lsum >= rt) { sC = (u32)lane; sAb = above; }
    __builtin_amdgcn_wave_barrier();
    const u32 C = sC, Ab = sAb;
    const u32 b4 = C * 256u + (u32)lane * 4u;
    u32 q0 = h2[b4], q1 = h2[b4 + 1], q2 = h2[b4 + 2], q3 = h2[b4 + 3];
    u32 s4 = q0 + q1 + q2 + q3;
    __builtin_amdgcn_wave_barrier();
    ls[lane] = s4;
    __builtin_amdgcn_wave_barrier();
    u32 ab2 = Ab;
    for (int l2 = lane + 1; l2 < 64; ++l2) ab2 += ls[l2];
    if (ab2 < rt && ab2 + s4 >= rt) {
      u32 acc = ab2;
      u32 bin2;
      if (acc + q3 >= rt)            bin2 = b4 + 3;
      else if (acc + q3 + q2 >= rt)  bin2 = b4 + 2;
      else if (acc + q3 + q2 + q1 >= rt) bin2 = b4 + 1;
      else                           bin2 = b4;
      sThr = (pref << 17) | (bin2 << 3);
    }
    __builtin_amdgcn_wave_barrier();
  }
  const u32 thr = sThr;

  // ---- ballot-prefix compaction of candidates >= thr (expected ~100-107)
  u32 cbase = 0;
  for (int i = lane; i < 8000; i += 64) {
    u32 v = vals[i];
    bool take = (v >= thr);
    u64 m = __ballot(take);
    if (take) {
      u32 pos = cbase + (u32)__popcll(m & ((1ull << lane) - 1ull));
      if (pos < 512u) cands[pos] = v;
    }
    cbase += (u32)__popcll(m);
  }
  __builtin_amdgcn_wave_barrier();
  const u32 nc = cbase;

  if (nc <= 512u) {
    // cands[nc..512) still zero from init; lockstep bitonic of 512 (desc)
    for (int k = 2; k <= 512; k <<= 1)
      for (int j = k >> 1; j > 0; j >>= 1) {
        for (int p = lane; p < 256; p += 64) {
          int i  = ((p & ~(j - 1)) << 1) | (p & (j - 1));
          int ix = i | j;
          bool up = (i & k) == 0;
          u32 a = cands[i], b = cands[ix];
          if (up ? (a < b) : (a > b)) { cands[i] = b; cands[ix] = a; }
        }
        __builtin_amdgcn_wave_barrier();
      }
    out[lane] = __uint_as_float(cands[lane]);
    if (lane < 36) out[lane + 64] = __uint_as_float(cands[lane + 64]);
  } else {
    // adversarial tie-flood: exact full sort of 8192 in h2/h1 space
    for (int i = lane; i < 8192; i += 64) h2[i] = (i < 8000) ? vals[i] : 0u;
    __builtin_amdgcn_wave_barrier();
    for (int k = 2; k <= 8192; k <<= 1)
      for (int j = k >> 1; j > 0; j >>= 1) {
        for (int p = lane; p < 4096; p += 64) {
          int i  = ((p & ~(j - 1)) << 1) | (p & (j - 1));
          int ix = i | j;
          bool up = (i & k) == 0;
          u32 a = h2[i], b = h2[ix];
          if (up ? (a < b) : (a > b)) { h2[i] = b; h2[ix] = a; }
        }
        __builtin_amdgcn_wave_barrier();
      }
    out[lane] = __uint_as_float(h2[lane]);
    if (lane < 36) out[lane + 64] = __uint_as_float(h2[lane + 64]);
  }
}

extern "C" void kernel_launch(void* const* d_in, const int* in_sizes, int n_in,
                              void* d_out, int out_size, void* d_ws, size_t ws_size,
                              hipStream_t stream) {
  const float* scores = (const float*)d_in[0];
  const float* boxes  = (const float*)d_in[1];
  float* out = (float*)d_out;
  char* ws = (char*)d_ws;

  u32* T16     = (u32*)(ws + OFF_T16);
  u32* prefA   = (u32*)(ws + OFF_PREFA);
  u32* tgtA    = (u32*)(ws + OFF_TGTA);
  u32* cnt     = (u32*)(ws + OFF_CNT);
  float* top_s = (float*)(ws + OFF_TOPS);
  u32* top_idx = (u32*)(ws + OFF_TOPI);
  float* cls_out = (float*)(ws + OFF_CLSOUT);
  u32* ghistA  = (u32*)(ws + OFF_GHA);
  u32* ghistB  = (u32*)(ws + OFF_GHB);
  u64* cand    = (u64*)(ws + OFF_CAND);
  u64* maskG   = (u64*)(ws + OFF_MASK);

  const bool bigws = (ws_size >= (size_t)OFF_MASK + MASK_BYTES);

  hipMemsetAsync(ws, 0, 1280, stream);
  hipMemsetAsync(ws + OFF_GHA, 0, 40960 + 81920, stream);
  hipMemsetAsync(cls_out, 0, N_CLS * 128 * sizeof(float), stream);

  k_histA<<<NBLK, 256, 0, stream>>>(scores, ghistA);
  k_thrA<<<1, 256, 0, stream>>>(ghistA, prefA, tgtA);
  k_histB<<<NBLK, 256, 0, stream>>>(scores, prefA, ghistB);
  k_thrB<<<1, 256, 0, stream>>>(ghistB, prefA, tgtA, T16);
  k_scatter<<<NBLK, 256, 0, stream>>>(scores, T16, cnt, cand);
  k_sort<<<N_CLS, 512, 0, stream>>>(cand, cnt, top_s, top_idx);
  if (bigws) {
    k_mask<<<dim3(N_CLS, 25), 256, 0, stream>>>(top_idx, boxes, maskG);
    k_sweep<<<N_CLS, 512, 0, stream>>>(top_s, maskG, cls_out);
  } else {
    k_nms<<<N_CLS, 1024, 0, stream>>>(top_s, top_idx, boxes, cls_out);
  }
  k_final<<<1, 64, 0, stream>>>(cls_out, out);
}

// Round 15
// 230.844 us; speedup vs baseline: 1.2520x; 1.2520x over previous
//
#include <hip/hip_runtime.h>
#include <stdint.h>

#define N_DET 20000
#define N_CLS 80
#define NELEM (N_DET * N_CLS)
#define TOPK  1000
#define CONF  0.05f
#define CANDS 1280
#define SORTN 2048
#define NBLK  40   // blocks for hist/scatter passes

typedef unsigned long long u64;
typedef unsigned int u32;

__device__ inline u64 shfl64(u64 v, int src) {
  int lo = __shfl((int)(u32)v, src, 64);
  int hi = __shfl((int)(v >> 32), src, 64);
  return ((u64)(u32)hi << 32) | (u32)lo;
}

// Exact replication of RN(inter/denom) > 0.5 without fdiv:
// RN(a/b) > 0.5  <=>  a/b > 0.5 + 2^-25 (tie rounds-to-even to 0.5)
//               <=>  a * 2^25 > b * (2^24 + 1), both products exact in f64.
__device__ __forceinline__ bool iou_gt_half(float4 bi, float ai,
                                            float4 bj, float aj) {
  #pragma clang fp contract(off)
  float iw = fmaxf(fminf(bi.z, bj.z) - fmaxf(bi.x, bj.x), 0.0f);
  float ih = fmaxf(fminf(bi.w, bj.w) - fmaxf(bi.y, bj.y), 0.0f);
  float inter = iw * ih;
  float denom = ai + aj - inter + 1e-9f;
  return (double)inter * 33554432.0 > (double)denom * 16777217.0;
}

// ---------------------------------------------------------------------------
// Workspace layout (small part total 1,624,320 B - NO overlaps):
//   T16 @0 (320) | prefA @320 | tgtA @640 | cnt @960
//   top_s @1280 (320000) | top_idx @321280 (320000) | cls_out @641280 (40960)
//   ghistA @682240 (40960) | ghistB @723200 (81920) | cand @805120 (819200)
//   maskG @1624320 (10,240,000)   [only if ws_size >= 11,864,320]
// ---------------------------------------------------------------------------
#define OFF_T16    0
#define OFF_PREFA  320
#define OFF_TGTA   640
#define OFF_CNT    960
#define OFF_TOPS   1280
#define OFF_TOPI   321280
#define OFF_CLSOUT 641280
#define OFF_GHA    682240
#define OFF_GHB    723200
#define OFF_CAND   805120
#define OFF_MASK   1624320
#define MASK_BYTES (80ull * TOPK * 16 * 8)

// ---------------------------------------------------------------------------
// Pass A: level-0 histogram, bins = float-bits >> 23 (clamped to 127).
// ---------------------------------------------------------------------------
__global__ __launch_bounds__(256) void k_histA(
    const float* __restrict__ S, u32* __restrict__ gh) {
  __shared__ u32 h[N_CLS * 129];
  for (int i = threadIdx.x; i < N_CLS * 129; i += 256) h[i] = 0;
  __syncthreads();
  const int per = NELEM / 4 / NBLK;
  const float4* S4 = (const float4*)S;
  const int v0 = blockIdx.x * per;
  for (int v = v0 + threadIdx.x; v < v0 + per; v += 256) {
    float4 f = S4[v];
    int c0 = (v * 4) % N_CLS;
    u32 b0 = __float_as_uint(f.x) >> 23; if (b0 > 127u) b0 = 127u;
    u32 b1 = __float_as_uint(f.y) >> 23; if (b1 > 127u) b1 = 127u;
    u32 b2 = __float_as_uint(f.z) >> 23; if (b2 > 127u) b2 = 127u;
    u32 b3 = __float_as_uint(f.w) >> 23; if (b3 > 127u) b3 = 127u;
    atomicAdd(&h[(c0 + 0) * 129 + b0], 1u);
    atomicAdd(&h[(c0 + 1) * 129 + b1], 1u);
    atomicAdd(&h[(c0 + 2) * 129 + b2], 1u);
    atomicAdd(&h[(c0 + 3) * 129 + b3], 1u);
  }
  __syncthreads();
  for (int i = threadIdx.x; i < N_CLS * 128; i += 256) {
    u32 v = h[(i >> 7) * 129 + (i & 127)];
    if (v) atomicAdd(&gh[i], v);
  }
}

__global__ __launch_bounds__(256) void k_thrA(
    const u32* __restrict__ gh, u32* __restrict__ prefA, u32* __restrict__ tgtA) {
  __shared__ u32 h[N_CLS * 129];
  for (int i = threadIdx.x; i < N_CLS * 128; i += 256)
    h[(i >> 7) * 129 + (i & 127)] = gh[i];
  __syncthreads();
  const int c = threadIdx.x;
  if (c >= N_CLS) return;
  u32 acc = 0;
  for (int b = 127; b >= 0; --b) {
    u32 hv = h[c * 129 + b];
    acc += hv;
    if (acc >= TOPK) { prefA[c] = (u32)b; tgtA[c] = TOPK - (acc - hv); return; }
  }
  prefA[c] = 0; tgtA[c] = TOPK;
}

// ---------------------------------------------------------------------------
// Pass B: level-1 histogram over bits [22:15] for elements in the level-0 bin.
// ---------------------------------------------------------------------------
__global__ __launch_bounds__(256) void k_histB(
    const float* __restrict__ S, const u32* __restrict__ prefA,
    u32* __restrict__ gh) {
  __shared__ u32 h[N_CLS * 257];
  __shared__ u32 pA[N_CLS];
  for (int i = threadIdx.x; i < N_CLS * 257; i += 256) h[i] = 0;
  for (int i = threadIdx.x; i < N_CLS; i += 256) pA[i] = prefA[i];
  __syncthreads();
  const int per = NELEM / 4 / NBLK;
  const float4* S4 = (const float4*)S;
  const int v0 = blockIdx.x * per;
  for (int v = v0 + threadIdx.x; v < v0 + per; v += 256) {
    float4 f = S4[v];
    int c0 = (v * 4) % N_CLS;
    u32 bb[4] = {__float_as_uint(f.x), __float_as_uint(f.y),
                 __float_as_uint(f.z), __float_as_uint(f.w)};
    #pragma unroll
    for (int k = 0; k < 4; ++k) {
      u32 e = bb[k] >> 23; if (e > 127u) e = 127u;
      if (e == pA[c0 + k])
        atomicAdd(&h[(c0 + k) * 257 + ((bb[k] >> 15) & 0xFF)], 1u);
    }
  }
  __syncthreads();
  for (int i = threadIdx.x; i < N_CLS * 256; i += 256) {
    u32 v = h[(i >> 8) * 257 + (i & 255)];
    if (v) atomicAdd(&gh[i], v);
  }
}

__global__ __launch_bounds__(256) void k_thrB(
    const u32* __restrict__ gh, const u32* __restrict__ prefA,
    const u32* __restrict__ tgtA, u32* __restrict__ T16) {
  __shared__ u32 h[N_CLS * 257];
  for (int i = threadIdx.x; i < N_CLS * 256; i += 256)
    h[(i >> 8) * 257 + (i & 255)] = gh[i];
  __syncthreads();
  const int c = threadIdx.x;
  if (c >= N_CLS) return;
  const u32 tgt = tgtA[c];
  u32 acc = 0, B1 = 0;
  for (int b = 255; b >= 0; --b) {
    acc += h[c * 257 + b];
    if (acc >= tgt) { B1 = (u32)b; break; }
  }
  T16[c] = (prefA[c] << 23) | (B1 << 15);
}

// ---------------------------------------------------------------------------
// Scatter, two-phase: LDS per-class count -> ONE global atomicAdd per
// (block,class) -> re-read + place at reserved offsets.
// ---------------------------------------------------------------------------
__global__ __launch_bounds__(256) void k_scatter(
    const float* __restrict__ S, const u32* __restrict__ T16,
    u32* __restrict__ cnt, u64* __restrict__ cand) {
  __shared__ u32 tl[N_CLS];
  __shared__ u32 lcnt[N_CLS];
  __shared__ u32 gbase[N_CLS];
  for (int i = threadIdx.x; i < N_CLS; i += 256) { tl[i] = T16[i]; lcnt[i] = 0; }
  __syncthreads();
  const int per = NELEM / 4 / NBLK;
  const float4* S4 = (const float4*)S;
  const int v0 = blockIdx.x * per;
  for (int v = v0 + threadIdx.x; v < v0 + per; v += 256) {
    float4 f = S4[v];
    const int c0 = (v * 4) % N_CLS;
    u32 bb[4] = {__float_as_uint(f.x), __float_as_uint(f.y),
                 __float_as_uint(f.z), __float_as_uint(f.w)};
    #pragma unroll
    for (int k = 0; k < 4; ++k)
      if (bb[k] >= tl[c0 + k]) atomicAdd(&lcnt[c0 + k], 1u);
  }
  __syncthreads();
  for (int i = threadIdx.x; i < N_CLS; i += 256) {
    u32 n = lcnt[i];
    gbase[i] = n ? atomicAdd(&cnt[i], n) : 0u;
    lcnt[i] = 0;
  }
  __syncthreads();
  for (int v = v0 + threadIdx.x; v < v0 + per; v += 256) {
    float4 f = S4[v];
    const int base = v * 4;
    const int c0 = base % N_CLS;
    const u32 row = (u32)(base / N_CLS);
    u32 bb[4] = {__float_as_uint(f.x), __float_as_uint(f.y),
                 __float_as_uint(f.z), __float_as_uint(f.w)};
    #pragma unroll
    for (int k = 0; k < 4; ++k) {
      if (bb[k] >= tl[c0 + k]) {
        u32 p = gbase[c0 + k] + atomicAdd(&lcnt[c0 + k], 1u);
        if (p < CANDS)
          cand[(size_t)(c0 + k) * CANDS + p] = ((u64)bb[k] << 32) | (u32)(~row);
      }
    }
  }
}

// ---------------------------------------------------------------------------
// Per-class bitonic sort -> top-1000 scores + box indices. 512 threads.
// ---------------------------------------------------------------------------
__global__ __launch_bounds__(512) void k_sort(
    const u64* __restrict__ cand, const u32* __restrict__ cnt,
    float* __restrict__ top_s, u32* __restrict__ top_idx) {
  const int c = blockIdx.x, t = threadIdx.x;
  __shared__ u64 keys[SORTN];
  u32 n = cnt[c]; if (n > CANDS) n = CANDS;
  for (int i = t; i < SORTN; i += 512)
    keys[i] = (i < (int)n) ? cand[(size_t)c * CANDS + i] : 0ull;
  __syncthreads();
  for (int k = 2; k <= SORTN; k <<= 1)
    for (int j = k >> 1; j > 0; j >>= 1) {
      for (int p = t; p < SORTN / 2; p += 512) {
        int i  = ((p & ~(j - 1)) << 1) | (p & (j - 1));
        int ix = i | j;
        bool up = (i & k) == 0;
        u64 a = keys[i], b = keys[ix];
        if (up ? (a < b) : (a > b)) { keys[i] = b; keys[ix] = a; }
      }
      __syncthreads();
    }
  for (int i = t; i < TOPK; i += 512) {
    u64 kk = keys[i];
    u32 idx = ~(u32)kk;
    if (kk == 0ull || idx >= N_DET) idx = 0;
    top_s[c * TOPK + i] = __uint_as_float((u32)(kk >> 32));
    top_idx[c * TOPK + i] = idx;
  }
}

// ---------------------------------------------------------------------------
// PATH P (big ws): mask kernel over the whole machine.
// Grid (80 classes, 25 row-blocks of 40 rows), 256 thr.
// ---------------------------------------------------------------------------
__global__ __launch_bounds__(256) void k_mask(
    const u32* __restrict__ top_idx, const float* __restrict__ boxes,
    u64* __restrict__ maskG) {
  const int c = blockIdx.x;
  const int tid = threadIdx.x, wave = tid >> 6, lane = tid & 63;
  __shared__ float4 sbox[TOPK];
  __shared__ float sarea[TOPK];
  for (int i = tid; i < TOPK; i += 256) {
    u32 idx = top_idx[c * TOPK + i];
    if (idx >= N_DET) idx = 0;
    float4 b = ((const float4*)boxes)[idx];
    sbox[i] = b;
    sarea[i] = (b.z - b.x) * (b.w - b.y);
  }
  __syncthreads();
  float4 cb[16]; float ca[16];
  #pragma unroll
  for (int s = 0; s < 16; ++s) {
    int j = s * 64 + lane;
    cb[s] = (j < TOPK) ? sbox[j] : make_float4(0.f, 0.f, 0.f, 0.f);
    ca[s] = (j < TOPK) ? sarea[j] : 0.f;
  }
  for (int rr = 0; rr < 10; ++rr) {
    const int i = blockIdx.y * 40 + wave * 10 + rr;
    float4 bi = sbox[i];
    float ai = sarea[i];
    const int s0 = i >> 6;
    u64 w = 0;
    #pragma unroll
    for (int s = 0; s < 16; ++s) {
      if (s >= s0) {
        int j = s * 64 + lane;
        bool sup = iou_gt_half(bi, ai, cb[s], ca[s]);
        if (s == s0) sup &= (j > i);
        u64 bal = __ballot(sup);
        if (lane == s) w = bal;
      }
    }
    if (lane < 16) maskG[((size_t)c * TOPK + i) * 16 + lane] = w;
  }
}

// ---------------------------------------------------------------------------
// PATH P: sweep v3 (512 thr): bulk LDS stage + 32-row word-batched resolve.
// ---------------------------------------------------------------------------
__global__ __launch_bounds__(512) void k_sweep(
    const float* __restrict__ top_s, const u64* __restrict__ maskG,
    float* __restrict__ cls_out) {
  const int c = blockIdx.x;
  const int tid = threadIdx.x, wave = tid >> 6, lane = tid & 63;
  __shared__ u64 maskL[TOPK * 16];  // 128000 B

  {
    const uint4* src = (const uint4*)(maskG + (size_t)c * TOPK * 16);
    uint4* dst = (uint4*)maskL;
    for (int i = tid; i < TOPK * 16 / 2; i += 512) dst[i] = src[i];
  }
  __syncthreads();

  if (wave == 0) {
    u64 kw = 0;
    for (int s = 0; s < 16; ++s) {
      int j = s * 64 + lane;
      bool valid = (j < TOPK) && (top_s[c * TOPK + j] > CONF);
      u64 bal = __ballot(valid);
      if (lane == s) kw = bal;
    }
    u32 keep32 = (u32)(shfl64(kw, lane >> 1) >> ((lane & 1) * 32));
    const u32* M32 = (const u32*)maskL;   // row i word w: M32[i*32 + w]
    const int li = lane & 31;

    u32 rcur[32], rnxt[32];
    #pragma unroll
    for (int d = 0; d < 32; ++d)
      rcur[d] = M32[d * 32 + li];

    for (int b = 0; b < 32; ++b) {
      if (b < 31) {
        #pragma unroll
        for (int d = 0; d < 32; ++d) {
          int row = (b + 1) * 32 + d;
          if (row >= TOPK) row = 0;
          rnxt[d] = M32[row * 32 + li];
        }
      }
      u32 w = __builtin_amdgcn_readlane(keep32, b);
      u32 kbits = 0u;
      #pragma unroll
      for (int d = 0; d < 32; ++d) {
        u32 rd = __builtin_amdgcn_readlane(rcur[d], b);
        u32 bit = (w >> d) & 1u;
        w &= ~(rd & (0u - bit));
        kbits |= bit << d;
      }
      u32 sup = 0u;
      #pragma unroll
      for (int d = 0; d < 32; ++d)
        sup |= rcur[d] & (0u - ((kbits >> d) & 1u));
      keep32 &= ~sup;
      #pragma unroll
      for (int d = 0; d < 32; ++d) rcur[d] = rnxt[d];
    }

    int base = 0;
    #pragma unroll
    for (int s = 0; s < 16; ++s) {
      u32 lo = __builtin_amdgcn_readlane(keep32, 2 * s);
      u32 hi = __builtin_amdgcn_readlane(keep32, 2 * s + 1);
      u64 w = ((u64)hi << 32) | lo;
      int pos = base + __popcll(w & ((1ull << lane) - 1ull));
      if (((w >> lane) & 1ull) && pos < 100)
        cls_out[c * 128 + pos] = top_s[c * TOPK + s * 64 + lane];
      base += __popcll(w);
    }
  }
}

// ---------------------------------------------------------------------------
// PATH Q (small ws): fused mask(LDS)+sweep, 16 waves, 1 block/CU.
// ---------------------------------------------------------------------------
__global__ __launch_bounds__(1024) void k_nms(
    const float* __restrict__ top_s, const u32* __restrict__ top_idx,
    const float* __restrict__ boxes, float* __restrict__ cls_out) {
  const int c = blockIdx.x;
  const int tid = threadIdx.x, wave = tid >> 6, lane = tid & 63;
  __shared__ float4 sbox[TOPK];
  __shared__ float sarea[TOPK];
  __shared__ u64 maskL[TOPK * 16];

  for (int i = tid; i < TOPK; i += 1024) {
    u32 idx = top_idx[c * TOPK + i];
    if (idx >= N_DET) idx = 0;
    float4 b = ((const float4*)boxes)[idx];
    sbox[i] = b;
    sarea[i] = (b.z - b.x) * (b.w - b.y);
  }
  __syncthreads();

  float4 cb[16]; float ca[16];
  #pragma unroll
  for (int s = 0; s < 16; ++s) {
    int j = s * 64 + lane;
    cb[s] = (j < TOPK) ? sbox[j] : make_float4(0.f, 0.f, 0.f, 0.f);
    ca[s] = (j < TOPK) ? sarea[j] : 0.f;
  }

  for (int i = wave; i < TOPK; i += 16) {
    float4 bi = sbox[i];
    float ai = sarea[i];
    const int s0 = i >> 6;
    u64 w = 0;
    #pragma unroll
    for (int s = 0; s < 16; ++s) {
      if (s >= s0) {
        int j = s * 64 + lane;
        bool sup = iou_gt_half(bi, ai, cb[s], ca[s]);
        if (s == s0) sup &= (j > i);
        u64 bal = __ballot(sup);
        if (lane == s) w = bal;
      }
    }
    if (lane < 16) maskL[i * 16 + lane] = w;
  }
  __syncthreads();

  if (wave == 0) {
    u64 kw = 0;
    for (int s = 0; s < 16; ++s) {
      int j = s * 64 + lane;
      bool valid = (j < TOPK) && (top_s[c * TOPK + j] > CONF);
      u64 bal = __ballot(valid);
      if (lane == s) kw = bal;
    }
    u32 keep32 = (u32)(shfl64(kw, lane >> 1) >> ((lane & 1) * 32));
    const u32* M32 = (const u32*)maskL;
    const bool ld = lane < 32;
    u32 rbuf[8];
    #pragma unroll
    for (int d = 0; d < 8; ++d)
      rbuf[d] = ld ? M32[d * 32 + lane] : 0u;
    for (int ib = 0; ib < TOPK; ib += 8) {
      #pragma unroll
      for (int d = 0; d < 8; ++d) {
        const int i = ib + d;
        u32 wv = __builtin_amdgcn_readlane(keep32, i >> 5);
        if ((wv >> (i & 31)) & 1u) keep32 &= ~rbuf[d];
        int nx = ib + 8 + d;
        rbuf[d] = (ld && nx < TOPK) ? M32[nx * 32 + lane] : 0u;
      }
    }
    int base = 0;
    #pragma unroll
    for (int s = 0; s < 16; ++s) {
      u32 lo = __builtin_amdgcn_readlane(keep32, 2 * s);
      u32 hi = __builtin_amdgcn_readlane(keep32, 2 * s + 1);
      u64 w = ((u64)hi << 32) | lo;
      int pos = base + __popcll(w & ((1ull << lane) - 1ull));
      if (((w >> lane) & 1ull) && pos < 100)
        cls_out[c * 128 + pos] = top_s[c * TOPK + s * 64 + lane];
      base += __popcll(w);
    }
  }
}

// ---------------------------------------------------------------------------
// Global top-100: hybrid two-level radix select, 1024 thr.
// R13 (256 thr, ~40 syncthreads) = 47 us; R14 (64 thr, 0 barriers) = 94 us
// -> need BOTH width and few barriers. Here: per-thread chunk sums,
// intra-wave suffix scan via __shfl_down (barrier-free), 16 wave-partials
// through tiny LDS (1 barrier per scan), owner resolves bin serially.
// Exactly 8 syncthreads on the hot path. Final sort: wave-0 lockstep
// bitonic-512. Fallback (nc>512, adversarial ties): multi-wave 8192 sort.
// ---------------------------------------------------------------------------
__global__ __launch_bounds__(1024) void k_final(
    const float* __restrict__ cls_out, float* __restrict__ out) {
  __shared__ u32 vals[8000];    // 32000 B
  __shared__ u32 h1[8192];      // 32768 B
  __shared__ u32 h2[16384];     // 65536 B
  __shared__ u32 wsum[16];
  __shared__ u32 cands[512];
  __shared__ u32 sPref, sT2, sThr, scnt;
  const int t = threadIdx.x, wave = t >> 6, lane = t & 63;

  uint4 z4 = make_uint4(0u, 0u, 0u, 0u);
  for (int i = t; i < 2048; i += 1024) ((uint4*)h1)[i] = z4;
  for (int i = t; i < 4096; i += 1024) ((uint4*)h2)[i] = z4;
  if (t < 128) ((uint4*)cands)[t] = z4;
  if (t == 0) { sPref = 0; sT2 = 1; sThr = 0; scnt = 0; }
  __syncthreads();  // B1

  // load + level-1 histogram of bits>>17 (zeros land in bin 0)
  for (int i = t; i < 8000; i += 1024) {
    u32 b = __float_as_uint(cls_out[(i / 100) * 128 + (i % 100)]);
    vals[i] = b;
    u32 bin = b >> 17; if (bin > 8191u) bin = 8191u;
    atomicAdd(&h1[bin], 1u);
  }
  __syncthreads();  // B2

  // ---- level-1 select (target 100): thread owns bins [8t, 8t+8)
  {
    const u32 b0 = (u32)t * 8u;
    u32 loc[8]; u32 lsum = 0;
    #pragma unroll
    for (int k = 0; k < 8; ++k) { loc[k] = h1[b0 + k]; lsum += loc[k]; }
    u32 s = lsum;  // intra-wave inclusive suffix scan (Kogge-Stone)
    #pragma unroll
    for (int off = 1; off < 64; off <<= 1) {
      u32 v = __shfl_down(s, off, 64);
      if (lane + off < 64) s += v;
    }
    if (lane == 0) wsum[wave] = s;
    __syncthreads();  // B3
    u32 aboveW = 0;
    #pragma unroll
    for (int w = 0; w < 16; ++w) if (w > wave) aboveW += wsum[w];
    u32 above = aboveW + (s - lsum);
    if (above < 100u && above + lsum >= 100u) {
      u32 acc = above;
      #pragma unroll
      for (int k = 7; k >= 0; --k) {
        acc += loc[k];
        if (acc >= 100u) { sPref = b0 + (u32)k; sT2 = 100u - (acc - loc[k]); break; }
      }
    }
    __syncthreads();  // B4
  }
  const u32 pref = sPref, rt = sT2;   // residual target in [1,100]

  // ---- level-2 histogram over bits[16:3] for elements in bin pref
  for (int i = t; i < 8000; i += 1024) {
    u32 b = vals[i];
    u32 bin = b >> 17; if (bin > 8191u) bin = 8191u;
    if (bin == pref) atomicAdd(&h2[(b >> 3) & 0x3FFFu], 1u);
  }
  __syncthreads();  // B5

  // ---- level-2 select (target rt): thread owns bins [16t, 16t+16)
  {
    const u32 b0 = (u32)t * 16u;
    u32 loc[16]; u32 lsum = 0;
    #pragma unroll
    for (int k = 0; k < 16; ++k) { loc[k] = h2[b0 + k]; lsum += loc[k]; }
    u32 s = lsum;
    #pragma unroll
    for (int off = 1; off < 64; off <<= 1) {
      u32 v = __shfl_down(s, off, 64);
      if (lane + off < 64) s += v;
    }
    if (lane == 0) wsum[wave] = s;
    __syncthreads();  // B6
    u32 aboveW = 0;
    #pragma unroll
    for (int w = 0; w < 16; ++w) if (w > wave) aboveW += wsum[w];
    u32 above = aboveW + (s - lsum);
    if (above < rt && above + lsum >= rt) {
      u32 acc = above;
      #pragma unroll
      for (int k = 15; k >= 0; --k) {
        acc += loc[k];
        if (acc >= rt) { sThr = (pref << 17) | ((b0 + (u32)k) << 3); break; }
      }
    }
    __syncthreads();  // B7
  }
  const u32 thr = sThr;

  // ---- compaction of candidates >= thr (expected ~100-107)
  for (int i = t; i < 8000; i += 1024) {
    u32 v = vals[i];
    if (v >= thr) {
      u32 p = atomicAdd(&scnt, 1u);
      if (p < 512u) cands[p] = v;
    }
  }
  __syncthreads();  // B8
  const u32 nc = scnt;

  if (nc <= 512u) {
    if (wave == 0) {
      // cands[nc..512) zero from init; wave-0 lockstep bitonic of 512 (desc)
      for (int k = 2; k <= 512; k <<= 1)
        for (int j = k >> 1; j > 0; j >>= 1) {
          for (int p = lane; p < 256; p += 64) {
            int i  = ((p & ~(j - 1)) << 1) | (p & (j - 1));
            int ix = i | j;
            bool up = (i & k) == 0;
            u32 a = cands[i], b = cands[ix];
            if (up ? (a < b) : (a > b)) { cands[i] = b; cands[ix] = a; }
          }
          __builtin_amdgcn_wave_barrier();
        }
      out[lane] = __uint_as_float(cands[lane]);
      if (lane < 36) out[lane + 64] = __uint_as_float(cands[lane + 64]);
    }
  } else {
    // adversarial tie-flood: exact full sort of 8192 in h2 (reuse as buffer)
    for (int i = t; i < 8192; i += 1024) h2[i] = (i < 8000) ? vals[i] : 0u;
    __syncthreads();
    for (int k = 2; k <= 8192; k <<= 1)
      for (int j = k >> 1; j > 0; j >>= 1) {
        for (int p = t; p < 4096; p += 1024) {
          int i  = ((p & ~(j - 1)) << 1) | (p & (j - 1));
          int ix = i | j;
          bool up = (i & k) == 0;
          u32 a = h2[i], b = h2[ix];
          if (up ? (a < b) : (a > b)) { h2[i] = b; h2[ix] = a; }
        }
        __syncthreads();
      }
    if (t < 100) out[t] = __uint_as_float(h2[t]);
  }
}

extern "C" void kernel_launch(void* const* d_in, const int* in_sizes, int n_in,
                              void* d_out, int out_size, void* d_ws, size_t ws_size,
                              hipStream_t stream) {
  const float* scores = (const float*)d_in[0];
  const float* boxes  = (const float*)d_in[1];
  float* out = (float*)d_out;
  char* ws = (char*)d_ws;

  u32* T16     = (u32*)(ws + OFF_T16);
  u32* prefA   = (u32*)(ws + OFF_PREFA);
  u32* tgtA    = (u32*)(ws + OFF_TGTA);
  u32* cnt     = (u32*)(ws + OFF_CNT);
  float* top_s = (float*)(ws + OFF_TOPS);
  u32* top_idx = (u32*)(ws + OFF_TOPI);
  float* cls_out = (float*)(ws + OFF_CLSOUT);
  u32* ghistA  = (u32*)(ws + OFF_GHA);
  u32* ghistB  = (u32*)(ws + OFF_GHB);
  u64* cand    = (u64*)(ws + OFF_CAND);
  u64* maskG   = (u64*)(ws + OFF_MASK);

  const bool bigws = (ws_size >= (size_t)OFF_MASK + MASK_BYTES);

  hipMemsetAsync(ws, 0, 1280, stream);
  hipMemsetAsync(ws + OFF_GHA, 0, 40960 + 81920, stream);
  hipMemsetAsync(cls_out, 0, N_CLS * 128 * sizeof(float), stream);

  k_histA<<<NBLK, 256, 0, stream>>>(scores, ghistA);
  k_thrA<<<1, 256, 0, stream>>>(ghistA, prefA, tgtA);
  k_histB<<<NBLK, 256, 0, stream>>>(scores, prefA, ghistB);
  k_thrB<<<1, 256, 0, stream>>>(ghistB, prefA, tgtA, T16);
  k_scatter<<<NBLK, 256, 0, stream>>>(scores, T16, cnt, cand);
  k_sort<<<N_CLS, 512, 0, stream>>>(cand, cnt, top_s, top_idx);
  if (bigws) {
    k_mask<<<dim3(N_CLS, 25), 256, 0, stream>>>(top_idx, boxes, maskG);
    k_sweep<<<N_CLS, 512, 0, stream>>>(top_s, maskG, cls_out);
  } else {
    k_nms<<<N_CLS, 1024, 0, stream>>>(top_s, top_idx, boxes, cls_out);
  }
  k_final<<<1, 1024, 0, stream>>>(cls_out, out);
}

// Round 16
// 198.797 us; speedup vs baseline: 1.4538x; 1.1612x over previous
//
#include <hip/hip_runtime.h>
#include <stdint.h>

#define N_DET 20000
#define N_CLS 80
#define NELEM (N_DET * N_CLS)
#define TOPK  1000
#define CONF  0.05f
#define CANDS 1280
#define SORTN 2048
#define NBLK  40   // blocks for hist/scatter passes

typedef unsigned long long u64;
typedef unsigned int u32;

__device__ inline u64 shfl64(u64 v, int src) {
  int lo = __shfl((int)(u32)v, src, 64);
  int hi = __shfl((int)(v >> 32), src, 64);
  return ((u64)(u32)hi << 32) | (u32)lo;
}

// Exact replication of RN(inter/denom) > 0.5 without fdiv:
// RN(a/b) > 0.5  <=>  a/b > 0.5 + 2^-25 (tie rounds-to-even to 0.5)
//               <=>  a * 2^25 > b * (2^24 + 1), both products exact in f64.
__device__ __forceinline__ bool iou_gt_half(float4 bi, float ai,
                                            float4 bj, float aj) {
  #pragma clang fp contract(off)
  float iw = fmaxf(fminf(bi.z, bj.z) - fmaxf(bi.x, bj.x), 0.0f);
  float ih = fmaxf(fminf(bi.w, bj.w) - fmaxf(bi.y, bj.y), 0.0f);
  float inter = iw * ih;
  float denom = ai + aj - inter + 1e-9f;
  return (double)inter * 33554432.0 > (double)denom * 16777217.0;
}

// ---------------------------------------------------------------------------
// Workspace layout (small part total 1,624,320 B - NO overlaps):
//   T16 @0 (320) | prefA @320 | tgtA @640 | cnt @960
//   top_s @1280 (320000) | top_idx @321280 (320000) | cls_out @641280 (40960)
//   ghistA @682240 (40960) | ghistB @723200 (81920) | cand @805120 (819200)
//   maskG @1624320 (10,240,000)   [only if ws_size >= 11,864,320]
// ---------------------------------------------------------------------------
#define OFF_T16    0
#define OFF_PREFA  320
#define OFF_TGTA   640
#define OFF_CNT    960
#define OFF_TOPS   1280
#define OFF_TOPI   321280
#define OFF_CLSOUT 641280
#define OFF_GHA    682240
#define OFF_GHB    723200
#define OFF_CAND   805120
#define OFF_MASK   1624320
#define MASK_BYTES (80ull * TOPK * 16 * 8)

// ---------------------------------------------------------------------------
// Pass A: level-0 histogram, bins = float-bits >> 23 (clamped to 127).
// ---------------------------------------------------------------------------
__global__ __launch_bounds__(256) void k_histA(
    const float* __restrict__ S, u32* __restrict__ gh) {
  __shared__ u32 h[N_CLS * 129];
  for (int i = threadIdx.x; i < N_CLS * 129; i += 256) h[i] = 0;
  __syncthreads();
  const int per = NELEM / 4 / NBLK;
  const float4* S4 = (const float4*)S;
  const int v0 = blockIdx.x * per;
  for (int v = v0 + threadIdx.x; v < v0 + per; v += 256) {
    float4 f = S4[v];
    int c0 = (v * 4) % N_CLS;
    u32 b0 = __float_as_uint(f.x) >> 23; if (b0 > 127u) b0 = 127u;
    u32 b1 = __float_as_uint(f.y) >> 23; if (b1 > 127u) b1 = 127u;
    u32 b2 = __float_as_uint(f.z) >> 23; if (b2 > 127u) b2 = 127u;
    u32 b3 = __float_as_uint(f.w) >> 23; if (b3 > 127u) b3 = 127u;
    atomicAdd(&h[(c0 + 0) * 129 + b0], 1u);
    atomicAdd(&h[(c0 + 1) * 129 + b1], 1u);
    atomicAdd(&h[(c0 + 2) * 129 + b2], 1u);
    atomicAdd(&h[(c0 + 3) * 129 + b3], 1u);
  }
  __syncthreads();
  for (int i = threadIdx.x; i < N_CLS * 128; i += 256) {
    u32 v = h[(i >> 7) * 129 + (i & 127)];
    if (v) atomicAdd(&gh[i], v);
  }
}

__global__ __launch_bounds__(256) void k_thrA(
    const u32* __restrict__ gh, u32* __restrict__ prefA, u32* __restrict__ tgtA) {
  __shared__ u32 h[N_CLS * 129];
  for (int i = threadIdx.x; i < N_CLS * 128; i += 256)
    h[(i >> 7) * 129 + (i & 127)] = gh[i];
  __syncthreads();
  const int c = threadIdx.x;
  if (c >= N_CLS) return;
  u32 acc = 0;
  for (int b = 127; b >= 0; --b) {
    u32 hv = h[c * 129 + b];
    acc += hv;
    if (acc >= TOPK) { prefA[c] = (u32)b; tgtA[c] = TOPK - (acc - hv); return; }
  }
  prefA[c] = 0; tgtA[c] = TOPK;
}

// ---------------------------------------------------------------------------
// Pass B: level-1 histogram over bits [22:15] for elements in the level-0 bin.
// ---------------------------------------------------------------------------
__global__ __launch_bounds__(256) void k_histB(
    const float* __restrict__ S, const u32* __restrict__ prefA,
    u32* __restrict__ gh) {
  __shared__ u32 h[N_CLS * 257];
  __shared__ u32 pA[N_CLS];
  for (int i = threadIdx.x; i < N_CLS * 257; i += 256) h[i] = 0;
  for (int i = threadIdx.x; i < N_CLS; i += 256) pA[i] = prefA[i];
  __syncthreads();
  const int per = NELEM / 4 / NBLK;
  const float4* S4 = (const float4*)S;
  const int v0 = blockIdx.x * per;
  for (int v = v0 + threadIdx.x; v < v0 + per; v += 256) {
    float4 f = S4[v];
    int c0 = (v * 4) % N_CLS;
    u32 bb[4] = {__float_as_uint(f.x), __float_as_uint(f.y),
                 __float_as_uint(f.z), __float_as_uint(f.w)};
    #pragma unroll
    for (int k = 0; k < 4; ++k) {
      u32 e = bb[k] >> 23; if (e > 127u) e = 127u;
      if (e == pA[c0 + k])
        atomicAdd(&h[(c0 + k) * 257 + ((bb[k] >> 15) & 0xFF)], 1u);
    }
  }
  __syncthreads();
  for (int i = threadIdx.x; i < N_CLS * 256; i += 256) {
    u32 v = h[(i >> 8) * 257 + (i & 255)];
    if (v) atomicAdd(&gh[i], v);
  }
}

__global__ __launch_bounds__(256) void k_thrB(
    const u32* __restrict__ gh, const u32* __restrict__ prefA,
    const u32* __restrict__ tgtA, u32* __restrict__ T16) {
  __shared__ u32 h[N_CLS * 257];
  for (int i = threadIdx.x; i < N_CLS * 256; i += 256)
    h[(i >> 8) * 257 + (i & 255)] = gh[i];
  __syncthreads();
  const int c = threadIdx.x;
  if (c >= N_CLS) return;
  const u32 tgt = tgtA[c];
  u32 acc = 0, B1 = 0;
  for (int b = 255; b >= 0; --b) {
    acc += h[c * 257 + b];
    if (acc >= tgt) { B1 = (u32)b; break; }
  }
  T16[c] = (prefA[c] << 23) | (B1 << 15);
}

// ---------------------------------------------------------------------------
// Scatter, two-phase: LDS per-class count -> ONE global atomicAdd per
// (block,class) -> re-read + place at reserved offsets.
// ---------------------------------------------------------------------------
__global__ __launch_bounds__(256) void k_scatter(
    const float* __restrict__ S, const u32* __restrict__ T16,
    u32* __restrict__ cnt, u64* __restrict__ cand) {
  __shared__ u32 tl[N_CLS];
  __shared__ u32 lcnt[N_CLS];
  __shared__ u32 gbase[N_CLS];
  for (int i = threadIdx.x; i < N_CLS; i += 256) { tl[i] = T16[i]; lcnt[i] = 0; }
  __syncthreads();
  const int per = NELEM / 4 / NBLK;
  const float4* S4 = (const float4*)S;
  const int v0 = blockIdx.x * per;
  for (int v = v0 + threadIdx.x; v < v0 + per; v += 256) {
    float4 f = S4[v];
    const int c0 = (v * 4) % N_CLS;
    u32 bb[4] = {__float_as_uint(f.x), __float_as_uint(f.y),
                 __float_as_uint(f.z), __float_as_uint(f.w)};
    #pragma unroll
    for (int k = 0; k < 4; ++k)
      if (bb[k] >= tl[c0 + k]) atomicAdd(&lcnt[c0 + k], 1u);
  }
  __syncthreads();
  for (int i = threadIdx.x; i < N_CLS; i += 256) {
    u32 n = lcnt[i];
    gbase[i] = n ? atomicAdd(&cnt[i], n) : 0u;
    lcnt[i] = 0;
  }
  __syncthreads();
  for (int v = v0 + threadIdx.x; v < v0 + per; v += 256) {
    float4 f = S4[v];
    const int base = v * 4;
    const int c0 = base % N_CLS;
    const u32 row = (u32)(base / N_CLS);
    u32 bb[4] = {__float_as_uint(f.x), __float_as_uint(f.y),
                 __float_as_uint(f.z), __float_as_uint(f.w)};
    #pragma unroll
    for (int k = 0; k < 4; ++k) {
      if (bb[k] >= tl[c0 + k]) {
        u32 p = gbase[c0 + k] + atomicAdd(&lcnt[c0 + k], 1u);
        if (p < CANDS)
          cand[(size_t)(c0 + k) * CANDS + p] = ((u64)bb[k] << 32) | (u32)(~row);
      }
    }
  }
}

// ---------------------------------------------------------------------------
// Per-class bitonic sort -> top-1000 scores + box indices. 512 threads.
// ---------------------------------------------------------------------------
__global__ __launch_bounds__(512) void k_sort(
    const u64* __restrict__ cand, const u32* __restrict__ cnt,
    float* __restrict__ top_s, u32* __restrict__ top_idx) {
  const int c = blockIdx.x, t = threadIdx.x;
  __shared__ u64 keys[SORTN];
  u32 n = cnt[c]; if (n > CANDS) n = CANDS;
  for (int i = t; i < SORTN; i += 512)
    keys[i] = (i < (int)n) ? cand[(size_t)c * CANDS + i] : 0ull;
  __syncthreads();
  for (int k = 2; k <= SORTN; k <<= 1)
    for (int j = k >> 1; j > 0; j >>= 1) {
      for (int p = t; p < SORTN / 2; p += 512) {
        int i  = ((p & ~(j - 1)) << 1) | (p & (j - 1));
        int ix = i | j;
        bool up = (i & k) == 0;
        u64 a = keys[i], b = keys[ix];
        if (up ? (a < b) : (a > b)) { keys[i] = b; keys[ix] = a; }
      }
      __syncthreads();
    }
  for (int i = t; i < TOPK; i += 512) {
    u64 kk = keys[i];
    u32 idx = ~(u32)kk;
    if (kk == 0ull || idx >= N_DET) idx = 0;
    top_s[c * TOPK + i] = __uint_as_float((u32)(kk >> 32));
    top_idx[c * TOPK + i] = idx;
  }
}

// ---------------------------------------------------------------------------
// PATH P (big ws): mask kernel over the whole machine.
// Grid (80 classes, 25 row-blocks of 40 rows), 256 thr.
// ---------------------------------------------------------------------------
__global__ __launch_bounds__(256) void k_mask(
    const u32* __restrict__ top_idx, const float* __restrict__ boxes,
    u64* __restrict__ maskG) {
  const int c = blockIdx.x;
  const int tid = threadIdx.x, wave = tid >> 6, lane = tid & 63;
  __shared__ float4 sbox[TOPK];
  __shared__ float sarea[TOPK];
  for (int i = tid; i < TOPK; i += 256) {
    u32 idx = top_idx[c * TOPK + i];
    if (idx >= N_DET) idx = 0;
    float4 b = ((const float4*)boxes)[idx];
    sbox[i] = b;
    sarea[i] = (b.z - b.x) * (b.w - b.y);
  }
  __syncthreads();
  float4 cb[16]; float ca[16];
  #pragma unroll
  for (int s = 0; s < 16; ++s) {
    int j = s * 64 + lane;
    cb[s] = (j < TOPK) ? sbox[j] : make_float4(0.f, 0.f, 0.f, 0.f);
    ca[s] = (j < TOPK) ? sarea[j] : 0.f;
  }
  for (int rr = 0; rr < 10; ++rr) {
    const int i = blockIdx.y * 40 + wave * 10 + rr;
    float4 bi = sbox[i];
    float ai = sarea[i];
    const int s0 = i >> 6;
    u64 w = 0;
    #pragma unroll
    for (int s = 0; s < 16; ++s) {
      if (s >= s0) {
        int j = s * 64 + lane;
        bool sup = iou_gt_half(bi, ai, cb[s], ca[s]);
        if (s == s0) sup &= (j > i);
        u64 bal = __ballot(sup);
        if (lane == s) w = bal;
      }
    }
    if (lane < 16) maskG[((size_t)c * TOPK + i) * 16 + lane] = w;
  }
}

// ---------------------------------------------------------------------------
// PATH P: sweep v4 (512 thr). R15: hot replays (mask L2-resident) take the
// SAME 43 us as cold -> not memory-bound; cost is staging 128 KB + 32 serial
// batches at low clock. Early exit: suppression only flows forward and rows
// are score-ordered, so once cumulative kept >= 100 the output is fully
// determined (unresolved later words are pos>=100-guarded in compaction).
// Stage only rows 0..255 eagerly; sweep batches 0..7 with early exit
// (typical data resolves by batch ~4); stage+sweep the tail only if needed.
// ---------------------------------------------------------------------------
__global__ __launch_bounds__(512) void k_sweep(
    const float* __restrict__ top_s, const u64* __restrict__ maskG,
    float* __restrict__ cls_out) {
  const int c = blockIdx.x;
  const int tid = threadIdx.x, wave = tid >> 6, lane = tid & 63;
  __shared__ u64 maskL[TOPK * 16];  // 128000 B
  __shared__ u32 sNeedTail;

  const uint4* src = (const uint4*)(maskG + (size_t)c * TOPK * 16);
  uint4* dst = (uint4*)maskL;
  // head: rows 0..255 = uint4 [0, 2048)
  for (int i = tid; i < 2048; i += 512) dst[i] = src[i];
  if (tid == 0) sNeedTail = 1u;
  __syncthreads();

  u32 keep32 = 0;
  u32 cum = 0;
  const u32* M32 = (const u32*)maskL;
  const int li = lane & 31;

  if (wave == 0) {
    u64 kw = 0;
    for (int s = 0; s < 16; ++s) {
      int j = s * 64 + lane;
      bool valid = (j < TOPK) && (top_s[c * TOPK + j] > CONF);
      u64 bal = __ballot(valid);
      if (lane == s) kw = bal;
    }
    keep32 = (u32)(shfl64(kw, lane >> 1) >> ((lane & 1) * 32));

    u32 rcur[32], rnxt[32];
    #pragma unroll
    for (int d = 0; d < 32; ++d) rcur[d] = M32[d * 32 + li];

    bool done = false;
    for (int b = 0; b < 8; ++b) {
      if (b < 7) {
        #pragma unroll
        for (int d = 0; d < 32; ++d)
          rnxt[d] = M32[((b + 1) * 32 + d) * 32 + li];
      }
      u32 w = __builtin_amdgcn_readlane(keep32, b);
      u32 kbits = 0u;
      #pragma unroll
      for (int d = 0; d < 32; ++d) {
        u32 rd = __builtin_amdgcn_readlane(rcur[d], b);
        u32 bit = (w >> d) & 1u;
        w &= ~(rd & (0u - bit));
        kbits |= bit << d;
      }
      u32 sup = 0u;
      #pragma unroll
      for (int d = 0; d < 32; ++d)
        sup |= rcur[d] & (0u - ((kbits >> d) & 1u));
      keep32 &= ~sup;
      cum += (u32)__popc(kbits);
      if (cum >= 100u) { done = true; break; }
      #pragma unroll
      for (int d = 0; d < 32; ++d) rcur[d] = rnxt[d];
    }
    if (done && lane == 0) sNeedTail = 0u;
  }
  __syncthreads();

  if (sNeedTail) {
    // tail: rows 256..999 = uint4 [2048, 8000)
    for (int i = 2048 + tid; i < 8000; i += 512) dst[i] = src[i];
    __syncthreads();
    if (wave == 0) {
      u32 rcur[32], rnxt[32];
      #pragma unroll
      for (int d = 0; d < 32; ++d) rcur[d] = M32[(256 + d) * 32 + li];
      for (int b = 8; b < 32 && cum < 100u; ++b) {
        if (b < 31) {
          #pragma unroll
          for (int d = 0; d < 32; ++d)
            rnxt[d] = M32[((b + 1) * 32 + d) * 32 + li];
        }
        u32 w = __builtin_amdgcn_readlane(keep32, b);
        u32 kbits = 0u;
        #pragma unroll
        for (int d = 0; d < 32; ++d) {
          u32 rd = __builtin_amdgcn_readlane(rcur[d], b);
          u32 bit = (w >> d) & 1u;
          w &= ~(rd & (0u - bit));
          kbits |= bit << d;
        }
        u32 sup = 0u;
        #pragma unroll
        for (int d = 0; d < 32; ++d)
          sup |= rcur[d] & (0u - ((kbits >> d) & 1u));
        keep32 &= ~sup;
        cum += (u32)__popc(kbits);
        #pragma unroll
        for (int d = 0; d < 32; ++d) rcur[d] = rnxt[d];
      }
    }
  }

  // compact first <=100 kept scores (cls_out pre-zeroed)
  if (wave == 0) {
    int base = 0;
    #pragma unroll
    for (int s = 0; s < 16; ++s) {
      u32 lo = __builtin_amdgcn_readlane(keep32, 2 * s);
      u32 hi = __builtin_amdgcn_readlane(keep32, 2 * s + 1);
      u64 w = ((u64)hi << 32) | lo;
      int pos = base + __popcll(w & ((1ull << lane) - 1ull));
      if (((w >> lane) & 1ull) && pos < 100)
        cls_out[c * 128 + pos] = top_s[c * TOPK + s * 64 + lane];
      base += __popcll(w);
    }
  }
}

// ---------------------------------------------------------------------------
// PATH Q (small ws): fused mask(LDS)+sweep, 16 waves, 1 block/CU.
// ---------------------------------------------------------------------------
__global__ __launch_bounds__(1024) void k_nms(
    const float* __restrict__ top_s, const u32* __restrict__ top_idx,
    const float* __restrict__ boxes, float* __restrict__ cls_out) {
  const int c = blockIdx.x;
  const int tid = threadIdx.x, wave = tid >> 6, lane = tid & 63;
  __shared__ float4 sbox[TOPK];
  __shared__ float sarea[TOPK];
  __shared__ u64 maskL[TOPK * 16];

  for (int i = tid; i < TOPK; i += 1024) {
    u32 idx = top_idx[c * TOPK + i];
    if (idx >= N_DET) idx = 0;
    float4 b = ((const float4*)boxes)[idx];
    sbox[i] = b;
    sarea[i] = (b.z - b.x) * (b.w - b.y);
  }
  __syncthreads();

  float4 cb[16]; float ca[16];
  #pragma unroll
  for (int s = 0; s < 16; ++s) {
    int j = s * 64 + lane;
    cb[s] = (j < TOPK) ? sbox[j] : make_float4(0.f, 0.f, 0.f, 0.f);
    ca[s] = (j < TOPK) ? sarea[j] : 0.f;
  }

  for (int i = wave; i < TOPK; i += 16) {
    float4 bi = sbox[i];
    float ai = sarea[i];
    const int s0 = i >> 6;
    u64 w = 0;
    #pragma unroll
    for (int s = 0; s < 16; ++s) {
      if (s >= s0) {
        int j = s * 64 + lane;
        bool sup = iou_gt_half(bi, ai, cb[s], ca[s]);
        if (s == s0) sup &= (j > i);
        u64 bal = __ballot(sup);
        if (lane == s) w = bal;
      }
    }
    if (lane < 16) maskL[i * 16 + lane] = w;
  }
  __syncthreads();

  if (wave == 0) {
    u64 kw = 0;
    for (int s = 0; s < 16; ++s) {
      int j = s * 64 + lane;
      bool valid = (j < TOPK) && (top_s[c * TOPK + j] > CONF);
      u64 bal = __ballot(valid);
      if (lane == s) kw = bal;
    }
    u32 keep32 = (u32)(shfl64(kw, lane >> 1) >> ((lane & 1) * 32));
    const u32* M32 = (const u32*)maskL;
    const bool ld = lane < 32;
    u32 rbuf[8];
    #pragma unroll
    for (int d = 0; d < 8; ++d)
      rbuf[d] = ld ? M32[d * 32 + lane] : 0u;
    for (int ib = 0; ib < TOPK; ib += 8) {
      #pragma unroll
      for (int d = 0; d < 8; ++d) {
        const int i = ib + d;
        u32 wv = __builtin_amdgcn_readlane(keep32, i >> 5);
        if ((wv >> (i & 31)) & 1u) keep32 &= ~rbuf[d];
        int nx = ib + 8 + d;
        rbuf[d] = (ld && nx < TOPK) ? M32[nx * 32 + lane] : 0u;
      }
    }
    int base = 0;
    #pragma unroll
    for (int s = 0; s < 16; ++s) {
      u32 lo = __builtin_amdgcn_readlane(keep32, 2 * s);
      u32 hi = __builtin_amdgcn_readlane(keep32, 2 * s + 1);
      u64 w = ((u64)hi << 32) | lo;
      int pos = base + __popcll(w & ((1ull << lane) - 1ull));
      if (((w >> lane) & 1ull) && pos < 100)
        cls_out[c * 128 + pos] = top_s[c * TOPK + s * 64 + lane];
      base += __popcll(w);
    }
  }
}

// ---------------------------------------------------------------------------
// Global top-100: hybrid two-level radix select, 1024 thr, 8 syncthreads.
// Per-thread chunk sums + intra-wave __shfl_down suffix scan + tiny LDS
// wave-partial table. Final sort: wave-0 lockstep bitonic-512.
// Fallback (nc>512, adversarial ties): multi-wave 8192 sort.
// ---------------------------------------------------------------------------
__global__ __launch_bounds__(1024) void k_final(
    const float* __restrict__ cls_out, float* __restrict__ out) {
  __shared__ u32 vals[8000];    // 32000 B
  __shared__ u32 h1[8192];      // 32768 B
  __shared__ u32 h2[16384];     // 65536 B
  __shared__ u32 wsum[16];
  __shared__ u32 cands[512];
  __shared__ u32 sPref, sT2, sThr, scnt;
  const int t = threadIdx.x, wave = t >> 6, lane = t & 63;

  uint4 z4 = make_uint4(0u, 0u, 0u, 0u);
  for (int i = t; i < 2048; i += 1024) ((uint4*)h1)[i] = z4;
  for (int i = t; i < 4096; i += 1024) ((uint4*)h2)[i] = z4;
  if (t < 128) ((uint4*)cands)[t] = z4;
  if (t == 0) { sPref = 0; sT2 = 1; sThr = 0; scnt = 0; }
  __syncthreads();  // B1

  for (int i = t; i < 8000; i += 1024) {
    u32 b = __float_as_uint(cls_out[(i / 100) * 128 + (i % 100)]);
    vals[i] = b;
    u32 bin = b >> 17; if (bin > 8191u) bin = 8191u;
    atomicAdd(&h1[bin], 1u);
  }
  __syncthreads();  // B2

  {
    const u32 b0 = (u32)t * 8u;
    u32 loc[8]; u32 lsum = 0;
    #pragma unroll
    for (int k = 0; k < 8; ++k) { loc[k] = h1[b0 + k]; lsum += loc[k]; }
    u32 s = lsum;
    #pragma unroll
    for (int off = 1; off < 64; off <<= 1) {
      u32 v = __shfl_down(s, off, 64);
      if (lane + off < 64) s += v;
    }
    if (lane == 0) wsum[wave] = s;
    __syncthreads();  // B3
    u32 aboveW = 0;
    #pragma unroll
    for (int w = 0; w < 16; ++w) if (w > wave) aboveW += wsum[w];
    u32 above = aboveW + (s - lsum);
    if (above < 100u && above + lsum >= 100u) {
      u32 acc = above;
      #pragma unroll
      for (int k = 7; k >= 0; --k) {
        acc += loc[k];
        if (acc >= 100u) { sPref = b0 + (u32)k; sT2 = 100u - (acc - loc[k]); break; }
      }
    }
    __syncthreads();  // B4
  }
  const u32 pref = sPref, rt = sT2;

  for (int i = t; i < 8000; i += 1024) {
    u32 b = vals[i];
    u32 bin = b >> 17; if (bin > 8191u) bin = 8191u;
    if (bin == pref) atomicAdd(&h2[(b >> 3) & 0x3FFFu], 1u);
  }
  __syncthreads();  // B5

  {
    const u32 b0 = (u32)t * 16u;
    u32 loc[16]; u32 lsum = 0;
    #pragma unroll
    for (int k = 0; k < 16; ++k) { loc[k] = h2[b0 + k]; lsum += loc[k]; }
    u32 s = lsum;
    #pragma unroll
    for (int off = 1; off < 64; off <<= 1) {
      u32 v = __shfl_down(s, off, 64);
      if (lane + off < 64) s += v;
    }
    if (lane == 0) wsum[wave] = s;
    __syncthreads();  // B6
    u32 aboveW = 0;
    #pragma unroll
    for (int w = 0; w < 16; ++w) if (w > wave) aboveW += wsum[w];
    u32 above = aboveW + (s - lsum);
    if (above < rt && above + lsum >= rt) {
      u32 acc = above;
      #pragma unroll
      for (int k = 15; k >= 0; --k) {
        acc += loc[k];
        if (acc >= rt) { sThr = (pref << 17) | ((b0 + (u32)k) << 3); break; }
      }
    }
    __syncthreads();  // B7
  }
  const u32 thr = sThr;

  for (int i = t; i < 8000; i += 1024) {
    u32 v = vals[i];
    if (v >= thr) {
      u32 p = atomicAdd(&scnt, 1u);
      if (p < 512u) cands[p] = v;
    }
  }
  __syncthreads();  // B8
  const u32 nc = scnt;

  if (nc <= 512u) {
    if (wave == 0) {
      for (int k = 2; k <= 512; k <<= 1)
        for (int j = k >> 1; j > 0; j >>= 1) {
          for (int p = lane; p < 256; p += 64) {
            int i  = ((p & ~(j - 1)) << 1) | (p & (j - 1));
            int ix = i | j;
            bool up = (i & k) == 0;
            u32 a = cands[i], b = cands[ix];
            if (up ? (a < b) : (a > b)) { cands[i] = b; cands[ix] = a; }
          }
          __builtin_amdgcn_wave_barrier();
        }
      out[lane] = __uint_as_float(cands[lane]);
      if (lane < 36) out[lane + 64] = __uint_as_float(cands[lane + 64]);
    }
  } else {
    for (int i = t; i < 8192; i += 1024) h2[i] = (i < 8000) ? vals[i] : 0u;
    __syncthreads();
    for (int k = 2; k <= 8192; k <<= 1)
      for (int j = k >> 1; j > 0; j >>= 1) {
        for (int p = t; p < 4096; p += 1024) {
          int i  = ((p & ~(j - 1)) << 1) | (p & (j - 1));
          int ix = i | j;
          bool up = (i & k) == 0;
          u32 a = h2[i], b = h2[ix];
          if (up ? (a < b) : (a > b)) { h2[i] = b; h2[ix] = a; }
        }
        __syncthreads();
      }
    if (t < 100) out[t] = __uint_as_float(h2[t]);
  }
}

extern "C" void kernel_launch(void* const* d_in, const int* in_sizes, int n_in,
                              void* d_out, int out_size, void* d_ws, size_t ws_size,
                              hipStream_t stream) {
  const float* scores = (const float*)d_in[0];
  const float* boxes  = (const float*)d_in[1];
  float* out = (float*)d_out;
  char* ws = (char*)d_ws;

  u32* T16     = (u32*)(ws + OFF_T16);
  u32* prefA   = (u32*)(ws + OFF_PREFA);
  u32* tgtA    = (u32*)(ws + OFF_TGTA);
  u32* cnt     = (u32*)(ws + OFF_CNT);
  float* top_s = (float*)(ws + OFF_TOPS);
  u32* top_idx = (u32*)(ws + OFF_TOPI);
  float* cls_out = (float*)(ws + OFF_CLSOUT);
  u32* ghistA  = (u32*)(ws + OFF_GHA);
  u32* ghistB  = (u32*)(ws + OFF_GHB);
  u64* cand    = (u64*)(ws + OFF_CAND);
  u64* maskG   = (u64*)(ws + OFF_MASK);

  const bool bigws = (ws_size >= (size_t)OFF_MASK + MASK_BYTES);

  hipMemsetAsync(ws, 0, 1280, stream);
  hipMemsetAsync(ws + OFF_GHA, 0, 40960 + 81920, stream);
  hipMemsetAsync(cls_out, 0, N_CLS * 128 * sizeof(float), stream);

  k_histA<<<NBLK, 256, 0, stream>>>(scores, ghistA);
  k_thrA<<<1, 256, 0, stream>>>(ghistA, prefA, tgtA);
  k_histB<<<NBLK, 256, 0, stream>>>(scores, prefA, ghistB);
  k_thrB<<<1, 256, 0, stream>>>(ghistB, prefA, tgtA, T16);
  k_scatter<<<NBLK, 256, 0, stream>>>(scores, T16, cnt, cand);
  k_sort<<<N_CLS, 512, 0, stream>>>(cand, cnt, top_s, top_idx);
  if (bigws) {
    k_mask<<<dim3(N_CLS, 25), 256, 0, stream>>>(top_idx, boxes, maskG);
    k_sweep<<<N_CLS, 512, 0, stream>>>(top_s, maskG, cls_out);
  } else {
    k_nms<<<N_CLS, 1024, 0, stream>>>(top_s, top_idx, boxes, cls_out);
  }
  k_final<<<1, 1024, 0, stream>>>(cls_out, out);
}

// Round 17
// 182.737 us; speedup vs baseline: 1.5816x; 1.0879x over previous
//
#include <hip/hip_runtime.h>
#include <stdint.h>

#define N_DET 20000
#define N_CLS 80
#define NELEM (N_DET * N_CLS)
#define TOPK  1000
#define CONF  0.05f
#define CANDS 1280
#define SORTN 2048
#define NBLK  40   // blocks for hist/scatter passes

typedef unsigned long long u64;
typedef unsigned int u32;

// Exact replication of RN(inter/denom) > 0.5 without fdiv:
// RN(a/b) > 0.5  <=>  a/b > 0.5 + 2^-25 (tie rounds-to-even to 0.5)
//               <=>  a * 2^25 > b * (2^24 + 1), both products exact in f64.
__device__ __forceinline__ bool iou_gt_half(float4 bi, float ai,
                                            float4 bj, float aj) {
  #pragma clang fp contract(off)
  float iw = fmaxf(fminf(bi.z, bj.z) - fmaxf(bi.x, bj.x), 0.0f);
  float ih = fmaxf(fminf(bi.w, bj.w) - fmaxf(bi.y, bj.y), 0.0f);
  float inter = iw * ih;
  float denom = ai + aj - inter + 1e-9f;
  return (double)inter * 33554432.0 > (double)denom * 16777217.0;
}

// ---------------------------------------------------------------------------
// Workspace layout (total 1,624,320 B - NO overlaps):
//   T16 @0 (320) | prefA @320 | tgtA @640 | cnt @960
//   top_s @1280 (320000) | top_idx @321280 (320000) | cls_out @641280 (40960)
//   ghistA @682240 (40960) | ghistB @723200 (81920) | cand @805120 (819200)
// ---------------------------------------------------------------------------
#define OFF_T16    0
#define OFF_PREFA  320
#define OFF_TGTA   640
#define OFF_CNT    960
#define OFF_TOPS   1280
#define OFF_TOPI   321280
#define OFF_CLSOUT 641280
#define OFF_GHA    682240
#define OFF_GHB    723200
#define OFF_CAND   805120

// ---------------------------------------------------------------------------
// Pass A: level-0 histogram, bins = float-bits >> 23 (clamped to 127).
// ---------------------------------------------------------------------------
__global__ __launch_bounds__(256) void k_histA(
    const float* __restrict__ S, u32* __restrict__ gh) {
  __shared__ u32 h[N_CLS * 129];
  for (int i = threadIdx.x; i < N_CLS * 129; i += 256) h[i] = 0;
  __syncthreads();
  const int per = NELEM / 4 / NBLK;
  const float4* S4 = (const float4*)S;
  const int v0 = blockIdx.x * per;
  for (int v = v0 + threadIdx.x; v < v0 + per; v += 256) {
    float4 f = S4[v];
    int c0 = (v * 4) % N_CLS;
    u32 b0 = __float_as_uint(f.x) >> 23; if (b0 > 127u) b0 = 127u;
    u32 b1 = __float_as_uint(f.y) >> 23; if (b1 > 127u) b1 = 127u;
    u32 b2 = __float_as_uint(f.z) >> 23; if (b2 > 127u) b2 = 127u;
    u32 b3 = __float_as_uint(f.w) >> 23; if (b3 > 127u) b3 = 127u;
    atomicAdd(&h[(c0 + 0) * 129 + b0], 1u);
    atomicAdd(&h[(c0 + 1) * 129 + b1], 1u);
    atomicAdd(&h[(c0 + 2) * 129 + b2], 1u);
    atomicAdd(&h[(c0 + 3) * 129 + b3], 1u);
  }
  __syncthreads();
  for (int i = threadIdx.x; i < N_CLS * 128; i += 256) {
    u32 v = h[(i >> 7) * 129 + (i & 127)];
    if (v) atomicAdd(&gh[i], v);
  }
}

__global__ __launch_bounds__(256) void k_thrA(
    const u32* __restrict__ gh, u32* __restrict__ prefA, u32* __restrict__ tgtA) {
  __shared__ u32 h[N_CLS * 129];
  for (int i = threadIdx.x; i < N_CLS * 128; i += 256)
    h[(i >> 7) * 129 + (i & 127)] = gh[i];
  __syncthreads();
  const int c = threadIdx.x;
  if (c >= N_CLS) return;
  u32 acc = 0;
  for (int b = 127; b >= 0; --b) {
    u32 hv = h[c * 129 + b];
    acc += hv;
    if (acc >= TOPK) { prefA[c] = (u32)b; tgtA[c] = TOPK - (acc - hv); return; }
  }
  prefA[c] = 0; tgtA[c] = TOPK;
}

// ---------------------------------------------------------------------------
// Pass B: level-1 histogram over bits [22:15] for elements in the level-0 bin.
// ---------------------------------------------------------------------------
__global__ __launch_bounds__(256) void k_histB(
    const float* __restrict__ S, const u32* __restrict__ prefA,
    u32* __restrict__ gh) {
  __shared__ u32 h[N_CLS * 257];
  __shared__ u32 pA[N_CLS];
  for (int i = threadIdx.x; i < N_CLS * 257; i += 256) h[i] = 0;
  for (int i = threadIdx.x; i < N_CLS; i += 256) pA[i] = prefA[i];
  __syncthreads();
  const int per = NELEM / 4 / NBLK;
  const float4* S4 = (const float4*)S;
  const int v0 = blockIdx.x * per;
  for (int v = v0 + threadIdx.x; v < v0 + per; v += 256) {
    float4 f = S4[v];
    int c0 = (v * 4) % N_CLS;
    u32 bb[4] = {__float_as_uint(f.x), __float_as_uint(f.y),
                 __float_as_uint(f.z), __float_as_uint(f.w)};
    #pragma unroll
    for (int k = 0; k < 4; ++k) {
      u32 e = bb[k] >> 23; if (e > 127u) e = 127u;
      if (e == pA[c0 + k])
        atomicAdd(&h[(c0 + k) * 257 + ((bb[k] >> 15) & 0xFF)], 1u);
    }
  }
  __syncthreads();
  for (int i = threadIdx.x; i < N_CLS * 256; i += 256) {
    u32 v = h[(i >> 8) * 257 + (i & 255)];
    if (v) atomicAdd(&gh[i], v);
  }
}

__global__ __launch_bounds__(256) void k_thrB(
    const u32* __restrict__ gh, const u32* __restrict__ prefA,
    const u32* __restrict__ tgtA, u32* __restrict__ T16) {
  __shared__ u32 h[N_CLS * 257];
  for (int i = threadIdx.x; i < N_CLS * 256; i += 256)
    h[(i >> 8) * 257 + (i & 255)] = gh[i];
  __syncthreads();
  const int c = threadIdx.x;
  if (c >= N_CLS) return;
  const u32 tgt = tgtA[c];
  u32 acc = 0, B1 = 0;
  for (int b = 255; b >= 0; --b) {
    acc += h[c * 257 + b];
    if (acc >= tgt) { B1 = (u32)b; break; }
  }
  T16[c] = (prefA[c] << 23) | (B1 << 15);
}

// ---------------------------------------------------------------------------
// Scatter, two-phase: LDS per-class count -> ONE global atomicAdd per
// (block,class) -> re-read + place at reserved offsets.
// ---------------------------------------------------------------------------
__global__ __launch_bounds__(256) void k_scatter(
    const float* __restrict__ S, const u32* __restrict__ T16,
    u32* __restrict__ cnt, u64* __restrict__ cand) {
  __shared__ u32 tl[N_CLS];
  __shared__ u32 lcnt[N_CLS];
  __shared__ u32 gbase[N_CLS];
  for (int i = threadIdx.x; i < N_CLS; i += 256) { tl[i] = T16[i]; lcnt[i] = 0; }
  __syncthreads();
  const int per = NELEM / 4 / NBLK;
  const float4* S4 = (const float4*)S;
  const int v0 = blockIdx.x * per;
  for (int v = v0 + threadIdx.x; v < v0 + per; v += 256) {
    float4 f = S4[v];
    const int c0 = (v * 4) % N_CLS;
    u32 bb[4] = {__float_as_uint(f.x), __float_as_uint(f.y),
                 __float_as_uint(f.z), __float_as_uint(f.w)};
    #pragma unroll
    for (int k = 0; k < 4; ++k)
      if (bb[k] >= tl[c0 + k]) atomicAdd(&lcnt[c0 + k], 1u);
  }
  __syncthreads();
  for (int i = threadIdx.x; i < N_CLS; i += 256) {
    u32 n = lcnt[i];
    gbase[i] = n ? atomicAdd(&cnt[i], n) : 0u;
    lcnt[i] = 0;
  }
  __syncthreads();
  for (int v = v0 + threadIdx.x; v < v0 + per; v += 256) {
    float4 f = S4[v];
    const int base = v * 4;
    const int c0 = base % N_CLS;
    const u32 row = (u32)(base / N_CLS);
    u32 bb[4] = {__float_as_uint(f.x), __float_as_uint(f.y),
                 __float_as_uint(f.z), __float_as_uint(f.w)};
    #pragma unroll
    for (int k = 0; k < 4; ++k) {
      if (bb[k] >= tl[c0 + k]) {
        u32 p = gbase[c0 + k] + atomicAdd(&lcnt[c0 + k], 1u);
        if (p < CANDS)
          cand[(size_t)(c0 + k) * CANDS + p] = ((u64)bb[k] << 32) | (u32)(~row);
      }
    }
  }
}

// ---------------------------------------------------------------------------
// Per-class bitonic sort -> top-1000 scores + box indices. 512 threads.
// ---------------------------------------------------------------------------
__global__ __launch_bounds__(512) void k_sort(
    const u64* __restrict__ cand, const u32* __restrict__ cnt,
    float* __restrict__ top_s, u32* __restrict__ top_idx) {
  const int c = blockIdx.x, t = threadIdx.x;
  __shared__ u64 keys[SORTN];
  u32 n = cnt[c]; if (n > CANDS) n = CANDS;
  for (int i = t; i < SORTN; i += 512)
    keys[i] = (i < (int)n) ? cand[(size_t)c * CANDS + i] : 0ull;
  __syncthreads();
  for (int k = 2; k <= SORTN; k <<= 1)
    for (int j = k >> 1; j > 0; j >>= 1) {
      for (int p = t; p < SORTN / 2; p += 512) {
        int i  = ((p & ~(j - 1)) << 1) | (p & (j - 1));
        int ix = i | j;
        bool up = (i & k) == 0;
        u64 a = keys[i], b = keys[ix];
        if (up ? (a < b) : (a > b)) { keys[i] = b; keys[ix] = a; }
      }
      __syncthreads();
    }
  for (int i = t; i < TOPK; i += 512) {
    u64 kk = keys[i];
    u32 idx = ~(u32)kk;
    if (kk == 0ull || idx >= N_DET) idx = 0;
    top_s[c * TOPK + i] = __uint_as_float((u32)(kk >> 32));
    top_idx[c * TOPK + i] = idx;
  }
}

// ---------------------------------------------------------------------------
// Greedy NMS, mask-free (replaces k_mask + k_sweep + 10 MB maskG).
// Equivalence: row i is kept iff valid(i) and no KEPT row k<i has
// iou(k,i)>0.5 (standard greedy == reference's forward-suppression loop;
// the iou formula is symmetric in the two boxes). Scores sorted desc ->
// valid is a prefix -> break at first score<=CONF. Stop at 100 kept:
// later kept rows can't enter the per-class top-100 nor affect earlier
// rows (suppression flows forward only) -- R15-proven exit rule.
// One block/class: 4 waves stage boxes+areas+scores to LDS; wave 0 runs
// the serial loop with kept boxes in lane registers (2 per lane) and
// one-row-ahead LDS prefetch. Typical ~110 rows x 1 ballot each.
// ---------------------------------------------------------------------------
__global__ __launch_bounds__(256) void k_nms(
    const float* __restrict__ top_s, const u32* __restrict__ top_idx,
    const float* __restrict__ boxes, float* __restrict__ cls_out) {
  const int c = blockIdx.x;
  const int tid = threadIdx.x, wave = tid >> 6, lane = tid & 63;
  __shared__ float4 sbox[TOPK];   // 16000 B
  __shared__ float sarea[TOPK];   //  4000 B
  __shared__ float sscore[TOPK];  //  4000 B

  for (int i = tid; i < TOPK; i += 256) {
    u32 idx = top_idx[c * TOPK + i];
    if (idx >= N_DET) idx = 0;
    float4 b = ((const float4*)boxes)[idx];
    sbox[i] = b;
    sarea[i] = (b.z - b.x) * (b.w - b.y);
    sscore[i] = top_s[c * TOPK + i];
  }
  __syncthreads();

  if (wave == 0) {
    float4 kb0 = make_float4(0.f, 0.f, 0.f, 0.f), kb1 = kb0;
    float ka0 = 0.f, ka1 = 0.f;
    int count = 0;
    // one-row-ahead prefetch
    float sc_n = sscore[0];
    float4 b_n = sbox[0];
    float a_n = sarea[0];
    for (int i = 0; i < TOPK && count < 100; ++i) {
      float sc = sc_n;
      float4 bi = b_n;
      float ai = a_n;
      if (i + 1 < TOPK) {  // issue next row's loads under this row's compute
        sc_n = sscore[i + 1];
        b_n = sbox[i + 1];
        a_n = sarea[i + 1];
      }
      if (!(sc > CONF)) break;  // sorted desc: all later rows invalid too
      bool sup0 = (lane < count) && iou_gt_half(kb0, ka0, bi, ai);
      bool sup1 = (lane + 64 < count) && iou_gt_half(kb1, ka1, bi, ai);
      u64 m = __ballot(sup0 || sup1);
      if (m == 0ull) {  // wave-uniform
        if (count < 64) {
          if (lane == count) { kb0 = bi; ka0 = ai; }
        } else {
          if (lane == count - 64) { kb1 = bi; ka1 = ai; }
        }
        if (lane == 0) cls_out[c * 128 + count] = sc;
        ++count;
      }
    }
  }
}

// ---------------------------------------------------------------------------
// Global top-100: hybrid two-level radix select, 1024 thr, 8 syncthreads.
// Per-thread chunk sums + intra-wave __shfl_down suffix scan + tiny LDS
// wave-partial table. Final sort: wave-0 lockstep bitonic-512.
// Fallback (nc>512, adversarial ties): multi-wave 8192 sort.
// ---------------------------------------------------------------------------
__global__ __launch_bounds__(1024) void k_final(
    const float* __restrict__ cls_out, float* __restrict__ out) {
  __shared__ u32 vals[8000];    // 32000 B
  __shared__ u32 h1[8192];      // 32768 B
  __shared__ u32 h2[16384];     // 65536 B
  __shared__ u32 wsum[16];
  __shared__ u32 cands[512];
  __shared__ u32 sPref, sT2, sThr, scnt;
  const int t = threadIdx.x, wave = t >> 6, lane = t & 63;

  uint4 z4 = make_uint4(0u, 0u, 0u, 0u);
  for (int i = t; i < 2048; i += 1024) ((uint4*)h1)[i] = z4;
  for (int i = t; i < 4096; i += 1024) ((uint4*)h2)[i] = z4;
  if (t < 128) ((uint4*)cands)[t] = z4;
  if (t == 0) { sPref = 0; sT2 = 1; sThr = 0; scnt = 0; }
  __syncthreads();  // B1

  for (int i = t; i < 8000; i += 1024) {
    u32 b = __float_as_uint(cls_out[(i / 100) * 128 + (i % 100)]);
    vals[i] = b;
    u32 bin = b >> 17; if (bin > 8191u) bin = 8191u;
    atomicAdd(&h1[bin], 1u);
  }
  __syncthreads();  // B2

  {
    const u32 b0 = (u32)t * 8u;
    u32 loc[8]; u32 lsum = 0;
    #pragma unroll
    for (int k = 0; k < 8; ++k) { loc[k] = h1[b0 + k]; lsum += loc[k]; }
    u32 s = lsum;
    #pragma unroll
    for (int off = 1; off < 64; off <<= 1) {
      u32 v = __shfl_down(s, off, 64);
      if (lane + off < 64) s += v;
    }
    if (lane == 0) wsum[wave] = s;
    __syncthreads();  // B3
    u32 aboveW = 0;
    #pragma unroll
    for (int w = 0; w < 16; ++w) if (w > wave) aboveW += wsum[w];
    u32 above = aboveW + (s - lsum);
    if (above < 100u && above + lsum >= 100u) {
      u32 acc = above;
      #pragma unroll
      for (int k = 7; k >= 0; --k) {
        acc += loc[k];
        if (acc >= 100u) { sPref = b0 + (u32)k; sT2 = 100u - (acc - loc[k]); break; }
      }
    }
    __syncthreads();  // B4
  }
  const u32 pref = sPref, rt = sT2;

  for (int i = t; i < 8000; i += 1024) {
    u32 b = vals[i];
    u32 bin = b >> 17; if (bin > 8191u) bin = 8191u;
    if (bin == pref) atomicAdd(&h2[(b >> 3) & 0x3FFFu], 1u);
  }
  __syncthreads();  // B5

  {
    const u32 b0 = (u32)t * 16u;
    u32 loc[16]; u32 lsum = 0;
    #pragma unroll
    for (int k = 0; k < 16; ++k) { loc[k] = h2[b0 + k]; lsum += loc[k]; }
    u32 s = lsum;
    #pragma unroll
    for (int off = 1; off < 64; off <<= 1) {
      u32 v = __shfl_down(s, off, 64);
      if (lane + off < 64) s += v;
    }
    if (lane == 0) wsum[wave] = s;
    __syncthreads();  // B6
    u32 aboveW = 0;
    #pragma unroll
    for (int w = 0; w < 16; ++w) if (w > wave) aboveW += wsum[w];
    u32 above = aboveW + (s - lsum);
    if (above < rt && above + lsum >= rt) {
      u32 acc = above;
      #pragma unroll
      for (int k = 15; k >= 0; --k) {
        acc += loc[k];
        if (acc >= rt) { sThr = (pref << 17) | ((b0 + (u32)k) << 3); break; }
      }
    }
    __syncthreads();  // B7
  }
  const u32 thr = sThr;

  for (int i = t; i < 8000; i += 1024) {
    u32 v = vals[i];
    if (v >= thr) {
      u32 p = atomicAdd(&scnt, 1u);
      if (p < 512u) cands[p] = v;
    }
  }
  __syncthreads();  // B8
  const u32 nc = scnt;

  if (nc <= 512u) {
    if (wave == 0) {
      for (int k = 2; k <= 512; k <<= 1)
        for (int j = k >> 1; j > 0; j >>= 1) {
          for (int p = lane; p < 256; p += 64) {
            int i  = ((p & ~(j - 1)) << 1) | (p & (j - 1));
            int ix = i | j;
            bool up = (i & k) == 0;
            u32 a = cands[i], b = cands[ix];
            if (up ? (a < b) : (a > b)) { cands[i] = b; cands[ix] = a; }
          }
          __builtin_amdgcn_wave_barrier();
        }
      out[lane] = __uint_as_float(cands[lane]);
      if (lane < 36) out[lane + 64] = __uint_as_float(cands[lane + 64]);
    }
  } else {
    for (int i = t; i < 8192; i += 1024) h2[i] = (i < 8000) ? vals[i] : 0u;
    __syncthreads();
    for (int k = 2; k <= 8192; k <<= 1)
      for (int j = k >> 1; j > 0; j >>= 1) {
        for (int p = t; p < 4096; p += 1024) {
          int i  = ((p & ~(j - 1)) << 1) | (p & (j - 1));
          int ix = i | j;
          bool up = (i & k) == 0;
          u32 a = h2[i], b = h2[ix];
          if (up ? (a < b) : (a > b)) { h2[i] = b; h2[ix] = a; }
        }
        __syncthreads();
      }
    if (t < 100) out[t] = __uint_as_float(h2[t]);
  }
}

extern "C" void kernel_launch(void* const* d_in, const int* in_sizes, int n_in,
                              void* d_out, int out_size, void* d_ws, size_t ws_size,
                              hipStream_t stream) {
  const float* scores = (const float*)d_in[0];
  const float* boxes  = (const float*)d_in[1];
  float* out = (float*)d_out;
  char* ws = (char*)d_ws;

  u32* T16     = (u32*)(ws + OFF_T16);
  u32* prefA   = (u32*)(ws + OFF_PREFA);
  u32* tgtA    = (u32*)(ws + OFF_TGTA);
  u32* cnt     = (u32*)(ws + OFF_CNT);
  float* top_s = (float*)(ws + OFF_TOPS);
  u32* top_idx = (u32*)(ws + OFF_TOPI);
  float* cls_out = (float*)(ws + OFF_CLSOUT);
  u32* ghistA  = (u32*)(ws + OFF_GHA);
  u32* ghistB  = (u32*)(ws + OFF_GHB);
  u64* cand    = (u64*)(ws + OFF_CAND);

  hipMemsetAsync(ws, 0, 1280, stream);
  hipMemsetAsync(ws + OFF_GHA, 0, 40960 + 81920, stream);
  hipMemsetAsync(cls_out, 0, N_CLS * 128 * sizeof(float), stream);

  k_histA<<<NBLK, 256, 0, stream>>>(scores, ghistA);
  k_thrA<<<1, 256, 0, stream>>>(ghistA, prefA, tgtA);
  k_histB<<<NBLK, 256, 0, stream>>>(scores, prefA, ghistB);
  k_thrB<<<1, 256, 0, stream>>>(ghistB, prefA, tgtA, T16);
  k_scatter<<<NBLK, 256, 0, stream>>>(scores, T16, cnt, cand);
  k_sort<<<N_CLS, 512, 0, stream>>>(cand, cnt, top_s, top_idx);
  k_nms<<<N_CLS, 256, 0, stream>>>(top_s, top_idx, boxes, cls_out);
  k_final<<<1, 1024, 0, stream>>>(cls_out, out);
}

// Round 18
// 157.210 us; speedup vs baseline: 1.8384x; 1.1624x over previous
//
#include <hip/hip_runtime.h>
#include <stdint.h>

#define N_DET 20000
#define N_CLS 80
#define NELEM (N_DET * N_CLS)
#define TOPK  1000
#define CONF  0.05f
#define CANDS 1280
#define SORTN 2048
#define NBLK  128  // blocks for hist/count/place passes (3125 float4 each)

typedef unsigned long long u64;
typedef unsigned int u32;

// Exact replication of RN(inter/denom) > 0.5 without fdiv:
// RN(a/b) > 0.5  <=>  a/b > 0.5 + 2^-25 (tie rounds-to-even to 0.5)
//               <=>  a * 2^25 > b * (2^24 + 1), both products exact in f64.
__device__ __forceinline__ bool iou_gt_half(float4 bi, float ai,
                                            float4 bj, float aj) {
  #pragma clang fp contract(off)
  float iw = fmaxf(fminf(bi.z, bj.z) - fmaxf(bi.x, bj.x), 0.0f);
  float ih = fmaxf(fminf(bi.w, bj.w) - fmaxf(bi.y, bj.y), 0.0f);
  float inter = iw * ih;
  float denom = ai + aj - inter + 1e-9f;
  return (double)inter * 33554432.0 > (double)denom * 16777217.0;
}

// ---------------------------------------------------------------------------
// Workspace layout (total 1,706,240 B - NO overlaps; ws >= 11.8 MB proven):
//   T16 @0 (320) | prefA @320 | tgtA @640 | cnt @960
//   top_s @1280 (320000) | top_idx @321280 (320000) | cls_out @641280 (40960)
//   ghistA @682240 (40960) | ghistB @723200 (81920) | cand @805120 (819200)
//   bcnt @1624320 (40960) | bbase @1665280 (40960)
// ---------------------------------------------------------------------------
#define OFF_T16    0
#define OFF_PREFA  320
#define OFF_TGTA   640
#define OFF_CNT    960
#define OFF_TOPS   1280
#define OFF_TOPI   321280
#define OFF_CLSOUT 641280
#define OFF_GHA    682240
#define OFF_GHB    723200
#define OFF_CAND   805120
#define OFF_BCNT   1624320
#define OFF_BBASE  1665280

// ---------------------------------------------------------------------------
// Pass A: level-0 histogram, bins = float-bits >> 23 (clamped to 127).
// ---------------------------------------------------------------------------
__global__ __launch_bounds__(256) void k_histA(
    const float* __restrict__ S, u32* __restrict__ gh) {
  __shared__ u32 h[N_CLS * 129];
  for (int i = threadIdx.x; i < N_CLS * 129; i += 256) h[i] = 0;
  __syncthreads();
  const int per = NELEM / 4 / NBLK;  // 3125
  const float4* S4 = (const float4*)S;
  const int v0 = blockIdx.x * per;
  for (int v = v0 + threadIdx.x; v < v0 + per; v += 256) {
    float4 f = S4[v];
    int c0 = (v * 4) % N_CLS;
    u32 b0 = __float_as_uint(f.x) >> 23; if (b0 > 127u) b0 = 127u;
    u32 b1 = __float_as_uint(f.y) >> 23; if (b1 > 127u) b1 = 127u;
    u32 b2 = __float_as_uint(f.z) >> 23; if (b2 > 127u) b2 = 127u;
    u32 b3 = __float_as_uint(f.w) >> 23; if (b3 > 127u) b3 = 127u;
    atomicAdd(&h[(c0 + 0) * 129 + b0], 1u);
    atomicAdd(&h[(c0 + 1) * 129 + b1], 1u);
    atomicAdd(&h[(c0 + 2) * 129 + b2], 1u);
    atomicAdd(&h[(c0 + 3) * 129 + b3], 1u);
  }
  __syncthreads();
  for (int i = threadIdx.x; i < N_CLS * 128; i += 256) {
    u32 v = h[(i >> 7) * 129 + (i & 127)];
    if (v) atomicAdd(&gh[i], v);
  }
}

__global__ __launch_bounds__(256) void k_thrA(
    const u32* __restrict__ gh, u32* __restrict__ prefA, u32* __restrict__ tgtA) {
  __shared__ u32 h[N_CLS * 129];
  for (int i = threadIdx.x; i < N_CLS * 128; i += 256)
    h[(i >> 7) * 129 + (i & 127)] = gh[i];
  __syncthreads();
  const int c = threadIdx.x;
  if (c >= N_CLS) return;
  u32 acc = 0;
  for (int b = 127; b >= 0; --b) {
    u32 hv = h[c * 129 + b];
    acc += hv;
    if (acc >= TOPK) { prefA[c] = (u32)b; tgtA[c] = TOPK - (acc - hv); return; }
  }
  prefA[c] = 0; tgtA[c] = TOPK;
}

// ---------------------------------------------------------------------------
// Pass B: level-1 histogram over bits [22:15] for elements in the level-0 bin.
// ---------------------------------------------------------------------------
__global__ __launch_bounds__(256) void k_histB(
    const float* __restrict__ S, const u32* __restrict__ prefA,
    u32* __restrict__ gh) {
  __shared__ u32 h[N_CLS * 257];
  __shared__ u32 pA[N_CLS];
  for (int i = threadIdx.x; i < N_CLS * 257; i += 256) h[i] = 0;
  for (int i = threadIdx.x; i < N_CLS; i += 256) pA[i] = prefA[i];
  __syncthreads();
  const int per = NELEM / 4 / NBLK;
  const float4* S4 = (const float4*)S;
  const int v0 = blockIdx.x * per;
  for (int v = v0 + threadIdx.x; v < v0 + per; v += 256) {
    float4 f = S4[v];
    int c0 = (v * 4) % N_CLS;
    u32 bb[4] = {__float_as_uint(f.x), __float_as_uint(f.y),
                 __float_as_uint(f.z), __float_as_uint(f.w)};
    #pragma unroll
    for (int k = 0; k < 4; ++k) {
      u32 e = bb[k] >> 23; if (e > 127u) e = 127u;
      if (e == pA[c0 + k])
        atomicAdd(&h[(c0 + k) * 257 + ((bb[k] >> 15) & 0xFF)], 1u);
    }
  }
  __syncthreads();
  for (int i = threadIdx.x; i < N_CLS * 256; i += 256) {
    u32 v = h[(i >> 8) * 257 + (i & 255)];
    if (v) atomicAdd(&gh[i], v);
  }
}

__global__ __launch_bounds__(256) void k_thrB(
    const u32* __restrict__ gh, const u32* __restrict__ prefA,
    const u32* __restrict__ tgtA, u32* __restrict__ T16) {
  __shared__ u32 h[N_CLS * 257];
  for (int i = threadIdx.x; i < N_CLS * 256; i += 256)
    h[(i >> 8) * 257 + (i & 255)] = gh[i];
  __syncthreads();
  const int c = threadIdx.x;
  if (c >= N_CLS) return;
  const u32 tgt = tgtA[c];
  u32 acc = 0, B1 = 0;
  for (int b = 255; b >= 0; --b) {
    acc += h[c * 257 + b];
    if (acc >= tgt) { B1 = (u32)b; break; }
  }
  T16[c] = (prefA[c] << 23) | (B1 << 15);
}

// ---------------------------------------------------------------------------
// Scatter, atomic-free hierarchical (R17: 40-block two-phase scatter was
// latency-bound at 1.5% occupancy; more blocks would re-create R4's
// contended-atomic disaster -> count/scan/place with NO global atomics).
// k_count: per-block per-class counts -> bcnt[b][c] (plain stores).
// ---------------------------------------------------------------------------
__global__ __launch_bounds__(256) void k_count(
    const float* __restrict__ S, const u32* __restrict__ T16,
    u32* __restrict__ bcnt) {
  __shared__ u32 tl[N_CLS];
  __shared__ u32 lcnt[N_CLS];
  for (int i = threadIdx.x; i < N_CLS; i += 256) { tl[i] = T16[i]; lcnt[i] = 0; }
  __syncthreads();
  const int per = NELEM / 4 / NBLK;
  const float4* S4 = (const float4*)S;
  const int v0 = blockIdx.x * per;
  for (int v = v0 + threadIdx.x; v < v0 + per; v += 256) {
    float4 f = S4[v];
    const int c0 = (v * 4) % N_CLS;
    u32 bb[4] = {__float_as_uint(f.x), __float_as_uint(f.y),
                 __float_as_uint(f.z), __float_as_uint(f.w)};
    #pragma unroll
    for (int k = 0; k < 4; ++k)
      if (bb[k] >= tl[c0 + k]) atomicAdd(&lcnt[c0 + k], 1u);
  }
  __syncthreads();
  for (int i = threadIdx.x; i < N_CLS; i += 256)
    bcnt[blockIdx.x * N_CLS + i] = lcnt[i];
}

// k_offsets: per-class exclusive prefix over the 128 block counts.
// One block, LDS-staged (128*80 u32 = 40960 B). Also writes cnt[c] totals.
__global__ __launch_bounds__(256) void k_offsets(
    const u32* __restrict__ bcnt, u32* __restrict__ bbase,
    u32* __restrict__ cnt) {
  __shared__ u32 l[NBLK * N_CLS];
  for (int i = threadIdx.x; i < NBLK * N_CLS; i += 256) l[i] = bcnt[i];
  __syncthreads();
  const int c = threadIdx.x;
  if (c >= N_CLS) return;
  u32 acc = 0;
  for (int b = 0; b < NBLK; ++b) {
    bbase[b * N_CLS + c] = acc;
    acc += l[b * N_CLS + c];
  }
  cnt[c] = acc;
}

// k_place: re-read (L2-hot) and place at bbase[b][c] + local LDS counter.
__global__ __launch_bounds__(256) void k_place(
    const float* __restrict__ S, const u32* __restrict__ T16,
    const u32* __restrict__ bbase, u64* __restrict__ cand) {
  __shared__ u32 tl[N_CLS];
  __shared__ u32 lcnt[N_CLS];
  __shared__ u32 gbase[N_CLS];
  for (int i = threadIdx.x; i < N_CLS; i += 256) {
    tl[i] = T16[i];
    lcnt[i] = 0;
    gbase[i] = bbase[blockIdx.x * N_CLS + i];
  }
  __syncthreads();
  const int per = NELEM / 4 / NBLK;
  const float4* S4 = (const float4*)S;
  const int v0 = blockIdx.x * per;
  for (int v = v0 + threadIdx.x; v < v0 + per; v += 256) {
    float4 f = S4[v];
    const int base = v * 4;
    const int c0 = base % N_CLS;
    const u32 row = (u32)(base / N_CLS);
    u32 bb[4] = {__float_as_uint(f.x), __float_as_uint(f.y),
                 __float_as_uint(f.z), __float_as_uint(f.w)};
    #pragma unroll
    for (int k = 0; k < 4; ++k) {
      if (bb[k] >= tl[c0 + k]) {
        u32 p = gbase[c0 + k] + atomicAdd(&lcnt[c0 + k], 1u);
        if (p < CANDS)
          cand[(size_t)(c0 + k) * CANDS + p] = ((u64)bb[k] << 32) | (u32)(~row);
      }
    }
  }
}

// ---------------------------------------------------------------------------
// Per-class bitonic sort -> top-1000 scores + box indices. 512 threads.
// ---------------------------------------------------------------------------
__global__ __launch_bounds__(512) void k_sort(
    const u64* __restrict__ cand, const u32* __restrict__ cnt,
    float* __restrict__ top_s, u32* __restrict__ top_idx) {
  const int c = blockIdx.x, t = threadIdx.x;
  __shared__ u64 keys[SORTN];
  u32 n = cnt[c]; if (n > CANDS) n = CANDS;
  for (int i = t; i < SORTN; i += 512)
    keys[i] = (i < (int)n) ? cand[(size_t)c * CANDS + i] : 0ull;
  __syncthreads();
  for (int k = 2; k <= SORTN; k <<= 1)
    for (int j = k >> 1; j > 0; j >>= 1) {
      for (int p = t; p < SORTN / 2; p += 512) {
        int i  = ((p & ~(j - 1)) << 1) | (p & (j - 1));
        int ix = i | j;
        bool up = (i & k) == 0;
        u64 a = keys[i], b = keys[ix];
        if (up ? (a < b) : (a > b)) { keys[i] = b; keys[ix] = a; }
      }
      __syncthreads();
    }
  for (int i = t; i < TOPK; i += 512) {
    u64 kk = keys[i];
    u32 idx = ~(u32)kk;
    if (kk == 0ull || idx >= N_DET) idx = 0;
    top_s[c * TOPK + i] = __uint_as_float((u32)(kk >> 32));
    top_idx[c * TOPK + i] = idx;
  }
}

// ---------------------------------------------------------------------------
// Greedy NMS, mask-free. Row i kept iff valid and no KEPT row k<i has
// iou>0.5 (== reference forward-suppression; iou symmetric). Scores sorted
// -> valid prefix -> break at score<=CONF. Stop at 100 kept (R15 rule).
// Wave 0: kept boxes in lane registers (2/lane), one-row-ahead prefetch.
// ---------------------------------------------------------------------------
__global__ __launch_bounds__(256) void k_nms(
    const float* __restrict__ top_s, const u32* __restrict__ top_idx,
    const float* __restrict__ boxes, float* __restrict__ cls_out) {
  const int c = blockIdx.x;
  const int tid = threadIdx.x, wave = tid >> 6, lane = tid & 63;
  __shared__ float4 sbox[TOPK];   // 16000 B
  __shared__ float sarea[TOPK];   //  4000 B
  __shared__ float sscore[TOPK];  //  4000 B

  for (int i = tid; i < TOPK; i += 256) {
    u32 idx = top_idx[c * TOPK + i];
    if (idx >= N_DET) idx = 0;
    float4 b = ((const float4*)boxes)[idx];
    sbox[i] = b;
    sarea[i] = (b.z - b.x) * (b.w - b.y);
    sscore[i] = top_s[c * TOPK + i];
  }
  __syncthreads();

  if (wave == 0) {
    float4 kb0 = make_float4(0.f, 0.f, 0.f, 0.f), kb1 = kb0;
    float ka0 = 0.f, ka1 = 0.f;
    int count = 0;
    float sc_n = sscore[0];
    float4 b_n = sbox[0];
    float a_n = sarea[0];
    for (int i = 0; i < TOPK && count < 100; ++i) {
      float sc = sc_n;
      float4 bi = b_n;
      float ai = a_n;
      if (i + 1 < TOPK) {
        sc_n = sscore[i + 1];
        b_n = sbox[i + 1];
        a_n = sarea[i + 1];
      }
      if (!(sc > CONF)) break;
      bool sup0 = (lane < count) && iou_gt_half(kb0, ka0, bi, ai);
      bool sup1 = (lane + 64 < count) && iou_gt_half(kb1, ka1, bi, ai);
      u64 m = __ballot(sup0 || sup1);
      if (m == 0ull) {
        if (count < 64) {
          if (lane == count) { kb0 = bi; ka0 = ai; }
        } else {
          if (lane == count - 64) { kb1 = bi; ka1 = ai; }
        }
        if (lane == 0) cls_out[c * 128 + count] = sc;
        ++count;
      }
    }
  }
}

// ---------------------------------------------------------------------------
// Global top-100: hybrid two-level radix select, 1024 thr, 8 syncthreads.
// Fallback (nc>512, adversarial ties): multi-wave 8192 sort.
// ---------------------------------------------------------------------------
__global__ __launch_bounds__(1024) void k_final(
    const float* __restrict__ cls_out, float* __restrict__ out) {
  __shared__ u32 vals[8000];
  __shared__ u32 h1[8192];
  __shared__ u32 h2[16384];
  __shared__ u32 wsum[16];
  __shared__ u32 cands[512];
  __shared__ u32 sPref, sT2, sThr, scnt;
  const int t = threadIdx.x, wave = t >> 6, lane = t & 63;

  uint4 z4 = make_uint4(0u, 0u, 0u, 0u);
  for (int i = t; i < 2048; i += 1024) ((uint4*)h1)[i] = z4;
  for (int i = t; i < 4096; i += 1024) ((uint4*)h2)[i] = z4;
  if (t < 128) ((uint4*)cands)[t] = z4;
  if (t == 0) { sPref = 0; sT2 = 1; sThr = 0; scnt = 0; }
  __syncthreads();  // B1

  for (int i = t; i < 8000; i += 1024) {
    u32 b = __float_as_uint(cls_out[(i / 100) * 128 + (i % 100)]);
    vals[i] = b;
    u32 bin = b >> 17; if (bin > 8191u) bin = 8191u;
    atomicAdd(&h1[bin], 1u);
  }
  __syncthreads();  // B2

  {
    const u32 b0 = (u32)t * 8u;
    u32 loc[8]; u32 lsum = 0;
    #pragma unroll
    for (int k = 0; k < 8; ++k) { loc[k] = h1[b0 + k]; lsum += loc[k]; }
    u32 s = lsum;
    #pragma unroll
    for (int off = 1; off < 64; off <<= 1) {
      u32 v = __shfl_down(s, off, 64);
      if (lane + off < 64) s += v;
    }
    if (lane == 0) wsum[wave] = s;
    __syncthreads();  // B3
    u32 aboveW = 0;
    #pragma unroll
    for (int w = 0; w < 16; ++w) if (w > wave) aboveW += wsum[w];
    u32 above = aboveW + (s - lsum);
    if (above < 100u && above + lsum >= 100u) {
      u32 acc = above;
      #pragma unroll
      for (int k = 7; k >= 0; --k) {
        acc += loc[k];
        if (acc >= 100u) { sPref = b0 + (u32)k; sT2 = 100u - (acc - loc[k]); break; }
      }
    }
    __syncthreads();  // B4
  }
  const u32 pref = sPref, rt = sT2;

  for (int i = t; i < 8000; i += 1024) {
    u32 b = vals[i];
    u32 bin = b >> 17; if (bin > 8191u) bin = 8191u;
    if (bin == pref) atomicAdd(&h2[(b >> 3) & 0x3FFFu], 1u);
  }
  __syncthreads();  // B5

  {
    const u32 b0 = (u32)t * 16u;
    u32 loc[16]; u32 lsum = 0;
    #pragma unroll
    for (int k = 0; k < 16; ++k) { loc[k] = h2[b0 + k]; lsum += loc[k]; }
    u32 s = lsum;
    #pragma unroll
    for (int off = 1; off < 64; off <<= 1) {
      u32 v = __shfl_down(s, off, 64);
      if (lane + off < 64) s += v;
    }
    if (lane == 0) wsum[wave] = s;
    __syncthreads();  // B6
    u32 aboveW = 0;
    #pragma unroll
    for (int w = 0; w < 16; ++w) if (w > wave) aboveW += wsum[w];
    u32 above = aboveW + (s - lsum);
    if (above < rt && above + lsum >= rt) {
      u32 acc = above;
      #pragma unroll
      for (int k = 15; k >= 0; --k) {
        acc += loc[k];
        if (acc >= rt) { sThr = (pref << 17) | ((b0 + (u32)k) << 3); break; }
      }
    }
    __syncthreads();  // B7
  }
  const u32 thr = sThr;

  for (int i = t; i < 8000; i += 1024) {
    u32 v = vals[i];
    if (v >= thr) {
      u32 p = atomicAdd(&scnt, 1u);
      if (p < 512u) cands[p] = v;
    }
  }
  __syncthreads();  // B8
  const u32 nc = scnt;

  if (nc <= 512u) {
    if (wave == 0) {
      for (int k = 2; k <= 512; k <<= 1)
        for (int j = k >> 1; j > 0; j >>= 1) {
          for (int p = lane; p < 256; p += 64) {
            int i  = ((p & ~(j - 1)) << 1) | (p & (j - 1));
            int ix = i | j;
            bool up = (i & k) == 0;
            u32 a = cands[i], b = cands[ix];
            if (up ? (a < b) : (a > b)) { cands[i] = b; cands[ix] = a; }
          }
          __builtin_amdgcn_wave_barrier();
        }
      out[lane] = __uint_as_float(cands[lane]);
      if (lane < 36) out[lane + 64] = __uint_as_float(cands[lane + 64]);
    }
  } else {
    for (int i = t; i < 8192; i += 1024) h2[i] = (i < 8000) ? vals[i] : 0u;
    __syncthreads();
    for (int k = 2; k <= 8192; k <<= 1)
      for (int j = k >> 1; j > 0; j >>= 1) {
        for (int p = t; p < 4096; p += 1024) {
          int i  = ((p & ~(j - 1)) << 1) | (p & (j - 1));
          int ix = i | j;
          bool up = (i & k) == 0;
          u32 a = h2[i], b = h2[ix];
          if (up ? (a < b) : (a > b)) { h2[i] = b; h2[ix] = a; }
        }
        __syncthreads();
      }
    if (t < 100) out[t] = __uint_as_float(h2[t]);
  }
}

extern "C" void kernel_launch(void* const* d_in, const int* in_sizes, int n_in,
                              void* d_out, int out_size, void* d_ws, size_t ws_size,
                              hipStream_t stream) {
  const float* scores = (const float*)d_in[0];
  const float* boxes  = (const float*)d_in[1];
  float* out = (float*)d_out;
  char* ws = (char*)d_ws;

  u32* T16     = (u32*)(ws + OFF_T16);
  u32* prefA   = (u32*)(ws + OFF_PREFA);
  u32* tgtA    = (u32*)(ws + OFF_TGTA);
  u32* cnt     = (u32*)(ws + OFF_CNT);
  float* top_s = (float*)(ws + OFF_TOPS);
  u32* top_idx = (u32*)(ws + OFF_TOPI);
  float* cls_out = (float*)(ws + OFF_CLSOUT);
  u32* ghistA  = (u32*)(ws + OFF_GHA);
  u32* ghistB  = (u32*)(ws + OFF_GHB);
  u64* cand    = (u64*)(ws + OFF_CAND);
  u32* bcnt    = (u32*)(ws + OFF_BCNT);
  u32* bbase   = (u32*)(ws + OFF_BBASE);

  hipMemsetAsync(ws, 0, 1280, stream);
  hipMemsetAsync(ws + OFF_GHA, 0, 40960 + 81920, stream);
  hipMemsetAsync(cls_out, 0, N_CLS * 128 * sizeof(float), stream);

  k_histA<<<NBLK, 256, 0, stream>>>(scores, ghistA);
  k_thrA<<<1, 256, 0, stream>>>(ghistA, prefA, tgtA);
  k_histB<<<NBLK, 256, 0, stream>>>(scores, prefA, ghistB);
  k_thrB<<<1, 256, 0, stream>>>(ghistB, prefA, tgtA, T16);
  k_count<<<NBLK, 256, 0, stream>>>(scores, T16, bcnt);
  k_offsets<<<1, 256, 0, stream>>>(bcnt, bbase, cnt);
  k_place<<<NBLK, 256, 0, stream>>>(scores, T16, bbase, cand);
  k_sort<<<N_CLS, 512, 0, stream>>>(cand, cnt, top_s, top_idx);
  k_nms<<<N_CLS, 256, 0, stream>>>(top_s, top_idx, boxes, cls_out);
  k_final<<<1, 1024, 0, stream>>>(cls_out, out);
}

// Round 19
// 154.169 us; speedup vs baseline: 1.8746x; 1.0197x over previous
//
#include <hip/hip_runtime.h>
#include <stdint.h>

#define N_DET 20000
#define N_CLS 80
#define NELEM (N_DET * N_CLS)
#define TOPK  1000
#define CONF  0.05f
#define CANDS 1280
#define SORTN 2048
#define NBLK  128  // blocks for hist/count/place passes (3125 float4 each)

typedef unsigned long long u64;
typedef unsigned int u32;

// Exact replication of RN(inter/denom) > 0.5 without fdiv:
// RN(a/b) > 0.5  <=>  a/b > 0.5 + 2^-25 (tie rounds-to-even to 0.5)
//               <=>  a * 2^25 > b * (2^24 + 1), both products exact in f64.
__device__ __forceinline__ bool iou_gt_half(float4 bi, float ai,
                                            float4 bj, float aj) {
  #pragma clang fp contract(off)
  float iw = fmaxf(fminf(bi.z, bj.z) - fmaxf(bi.x, bj.x), 0.0f);
  float ih = fmaxf(fminf(bi.w, bj.w) - fmaxf(bi.y, bj.y), 0.0f);
  float inter = iw * ih;
  float denom = ai + aj - inter + 1e-9f;
  return (double)inter * 33554432.0 > (double)denom * 16777217.0;
}

// ---------------------------------------------------------------------------
// Workspace layout (total 1,706,240 B - NO overlaps):
//   T16 @0 (320) | prefA @320 | tgtA @640 | cnt @960      [fully overwritten
//   each call by k_thrA/k_thrB/k_offsets -> no zeroing needed]
//   top_s @1280 (320000) | top_idx @321280 (320000) | cls_out @641280 (40960)
//   ghistA @682240 (40960) | ghistB @723200 (81920)       [zeroed by k_zero]
//   cand @805120 (819200) | bcnt @1624320 (40960) | bbase @1665280 (40960)
// ---------------------------------------------------------------------------
#define OFF_T16    0
#define OFF_PREFA  320
#define OFF_TGTA   640
#define OFF_CNT    960
#define OFF_TOPS   1280
#define OFF_TOPI   321280
#define OFF_CLSOUT 641280
#define OFF_GHA    682240
#define OFF_GHB    723200
#define OFF_CAND   805120
#define OFF_BCNT   1624320
#define OFF_BBASE  1665280

// Zero ghistA+ghistB (contiguous 122880 B = 7680 uint4).
__global__ __launch_bounds__(256) void k_zero(u32* __restrict__ gh) {
  uint4 z4 = make_uint4(0u, 0u, 0u, 0u);
  uint4* p = (uint4*)gh;
  int i = blockIdx.x * 256 + threadIdx.x;
  if (i < 7680) p[i] = z4;
}

// ---------------------------------------------------------------------------
// Pass A: level-0 histogram, bins = float-bits >> 23 (clamped to 127).
// ---------------------------------------------------------------------------
__global__ __launch_bounds__(256) void k_histA(
    const float* __restrict__ S, u32* __restrict__ gh) {
  __shared__ u32 h[N_CLS * 129];
  for (int i = threadIdx.x; i < N_CLS * 129; i += 256) h[i] = 0;
  __syncthreads();
  const int per = NELEM / 4 / NBLK;  // 3125
  const float4* S4 = (const float4*)S;
  const int v0 = blockIdx.x * per;
  for (int v = v0 + threadIdx.x; v < v0 + per; v += 256) {
    float4 f = S4[v];
    int c0 = (v * 4) % N_CLS;
    u32 b0 = __float_as_uint(f.x) >> 23; if (b0 > 127u) b0 = 127u;
    u32 b1 = __float_as_uint(f.y) >> 23; if (b1 > 127u) b1 = 127u;
    u32 b2 = __float_as_uint(f.z) >> 23; if (b2 > 127u) b2 = 127u;
    u32 b3 = __float_as_uint(f.w) >> 23; if (b3 > 127u) b3 = 127u;
    atomicAdd(&h[(c0 + 0) * 129 + b0], 1u);
    atomicAdd(&h[(c0 + 1) * 129 + b1], 1u);
    atomicAdd(&h[(c0 + 2) * 129 + b2], 1u);
    atomicAdd(&h[(c0 + 3) * 129 + b3], 1u);
  }
  __syncthreads();
  for (int i = threadIdx.x; i < N_CLS * 128; i += 256) {
    u32 v = h[(i >> 7) * 129 + (i & 127)];
    if (v) atomicAdd(&gh[i], v);
  }
}

__global__ __launch_bounds__(256) void k_thrA(
    const u32* __restrict__ gh, u32* __restrict__ prefA, u32* __restrict__ tgtA) {
  __shared__ u32 h[N_CLS * 129];
  for (int i = threadIdx.x; i < N_CLS * 128; i += 256)
    h[(i >> 7) * 129 + (i & 127)] = gh[i];
  __syncthreads();
  const int c = threadIdx.x;
  if (c >= N_CLS) return;
  u32 acc = 0;
  for (int b = 127; b >= 0; --b) {
    u32 hv = h[c * 129 + b];
    acc += hv;
    if (acc >= TOPK) { prefA[c] = (u32)b; tgtA[c] = TOPK - (acc - hv); return; }
  }
  prefA[c] = 0; tgtA[c] = TOPK;
}

// ---------------------------------------------------------------------------
// Pass B: level-1 histogram over bits [22:15] for elements in the level-0 bin.
// ---------------------------------------------------------------------------
__global__ __launch_bounds__(256) void k_histB(
    const float* __restrict__ S, const u32* __restrict__ prefA,
    u32* __restrict__ gh) {
  __shared__ u32 h[N_CLS * 257];
  __shared__ u32 pA[N_CLS];
  for (int i = threadIdx.x; i < N_CLS * 257; i += 256) h[i] = 0;
  for (int i = threadIdx.x; i < N_CLS; i += 256) pA[i] = prefA[i];
  __syncthreads();
  const int per = NELEM / 4 / NBLK;
  const float4* S4 = (const float4*)S;
  const int v0 = blockIdx.x * per;
  for (int v = v0 + threadIdx.x; v < v0 + per; v += 256) {
    float4 f = S4[v];
    int c0 = (v * 4) % N_CLS;
    u32 bb[4] = {__float_as_uint(f.x), __float_as_uint(f.y),
                 __float_as_uint(f.z), __float_as_uint(f.w)};
    #pragma unroll
    for (int k = 0; k < 4; ++k) {
      u32 e = bb[k] >> 23; if (e > 127u) e = 127u;
      if (e == pA[c0 + k])
        atomicAdd(&h[(c0 + k) * 257 + ((bb[k] >> 15) & 0xFF)], 1u);
    }
  }
  __syncthreads();
  for (int i = threadIdx.x; i < N_CLS * 256; i += 256) {
    u32 v = h[(i >> 8) * 257 + (i & 255)];
    if (v) atomicAdd(&gh[i], v);
  }
}

__global__ __launch_bounds__(256) void k_thrB(
    const u32* __restrict__ gh, const u32* __restrict__ prefA,
    const u32* __restrict__ tgtA, u32* __restrict__ T16) {
  __shared__ u32 h[N_CLS * 257];
  for (int i = threadIdx.x; i < N_CLS * 256; i += 256)
    h[(i >> 8) * 257 + (i & 255)] = gh[i];
  __syncthreads();
  const int c = threadIdx.x;
  if (c >= N_CLS) return;
  const u32 tgt = tgtA[c];
  u32 acc = 0, B1 = 0;
  for (int b = 255; b >= 0; --b) {
    acc += h[c * 257 + b];
    if (acc >= tgt) { B1 = (u32)b; break; }
  }
  T16[c] = (prefA[c] << 23) | (B1 << 15);
}

// ---------------------------------------------------------------------------
// Scatter, atomic-free hierarchical: count -> scan -> place.
// ---------------------------------------------------------------------------
__global__ __launch_bounds__(256) void k_count(
    const float* __restrict__ S, const u32* __restrict__ T16,
    u32* __restrict__ bcnt) {
  __shared__ u32 tl[N_CLS];
  __shared__ u32 lcnt[N_CLS];
  for (int i = threadIdx.x; i < N_CLS; i += 256) { tl[i] = T16[i]; lcnt[i] = 0; }
  __syncthreads();
  const int per = NELEM / 4 / NBLK;
  const float4* S4 = (const float4*)S;
  const int v0 = blockIdx.x * per;
  for (int v = v0 + threadIdx.x; v < v0 + per; v += 256) {
    float4 f = S4[v];
    const int c0 = (v * 4) % N_CLS;
    u32 bb[4] = {__float_as_uint(f.x), __float_as_uint(f.y),
                 __float_as_uint(f.z), __float_as_uint(f.w)};
    #pragma unroll
    for (int k = 0; k < 4; ++k)
      if (bb[k] >= tl[c0 + k]) atomicAdd(&lcnt[c0 + k], 1u);
  }
  __syncthreads();
  for (int i = threadIdx.x; i < N_CLS; i += 256)
    bcnt[blockIdx.x * N_CLS + i] = lcnt[i];
}

__global__ __launch_bounds__(256) void k_offsets(
    const u32* __restrict__ bcnt, u32* __restrict__ bbase,
    u32* __restrict__ cnt) {
  __shared__ u32 l[NBLK * N_CLS];
  for (int i = threadIdx.x; i < NBLK * N_CLS; i += 256) l[i] = bcnt[i];
  __syncthreads();
  const int c = threadIdx.x;
  if (c >= N_CLS) return;
  u32 acc = 0;
  for (int b = 0; b < NBLK; ++b) {
    bbase[b * N_CLS + c] = acc;
    acc += l[b * N_CLS + c];
  }
  cnt[c] = acc;
}

__global__ __launch_bounds__(256) void k_place(
    const float* __restrict__ S, const u32* __restrict__ T16,
    const u32* __restrict__ bbase, u64* __restrict__ cand) {
  __shared__ u32 tl[N_CLS];
  __shared__ u32 lcnt[N_CLS];
  __shared__ u32 gbase[N_CLS];
  for (int i = threadIdx.x; i < N_CLS; i += 256) {
    tl[i] = T16[i];
    lcnt[i] = 0;
    gbase[i] = bbase[blockIdx.x * N_CLS + i];
  }
  __syncthreads();
  const int per = NELEM / 4 / NBLK;
  const float4* S4 = (const float4*)S;
  const int v0 = blockIdx.x * per;
  for (int v = v0 + threadIdx.x; v < v0 + per; v += 256) {
    float4 f = S4[v];
    const int base = v * 4;
    const int c0 = base % N_CLS;
    const u32 row = (u32)(base / N_CLS);
    u32 bb[4] = {__float_as_uint(f.x), __float_as_uint(f.y),
                 __float_as_uint(f.z), __float_as_uint(f.w)};
    #pragma unroll
    for (int k = 0; k < 4; ++k) {
      if (bb[k] >= tl[c0 + k]) {
        u32 p = gbase[c0 + k] + atomicAdd(&lcnt[c0 + k], 1u);
        if (p < CANDS)
          cand[(size_t)(c0 + k) * CANDS + p] = ((u64)bb[k] << 32) | (u32)(~row);
      }
    }
  }
}

// ---------------------------------------------------------------------------
// Per-class bitonic sort -> top-1000 scores + box indices. 512 threads.
// Only slots < cnt[c] of cand are read (stale tail never touched).
// ---------------------------------------------------------------------------
__global__ __launch_bounds__(512) void k_sort(
    const u64* __restrict__ cand, const u32* __restrict__ cnt,
    float* __restrict__ top_s, u32* __restrict__ top_idx) {
  const int c = blockIdx.x, t = threadIdx.x;
  __shared__ u64 keys[SORTN];
  u32 n = cnt[c]; if (n > CANDS) n = CANDS;
  for (int i = t; i < SORTN; i += 512)
    keys[i] = (i < (int)n) ? cand[(size_t)c * CANDS + i] : 0ull;
  __syncthreads();
  for (int k = 2; k <= SORTN; k <<= 1)
    for (int j = k >> 1; j > 0; j >>= 1) {
      for (int p = t; p < SORTN / 2; p += 512) {
        int i  = ((p & ~(j - 1)) << 1) | (p & (j - 1));
        int ix = i | j;
        bool up = (i & k) == 0;
        u64 a = keys[i], b = keys[ix];
        if (up ? (a < b) : (a > b)) { keys[i] = b; keys[ix] = a; }
      }
      __syncthreads();
    }
  for (int i = t; i < TOPK; i += 512) {
    u64 kk = keys[i];
    u32 idx = ~(u32)kk;
    if (kk == 0ull || idx >= N_DET) idx = 0;
    top_s[c * TOPK + i] = __uint_as_float((u32)(kk >> 32));
    top_idx[c * TOPK + i] = idx;
  }
}

// ---------------------------------------------------------------------------
// Greedy NMS, mask-free. Row i kept iff valid and no KEPT row k<i has
// iou>0.5. Stop at 100 kept (R15 rule) or first score<=CONF (sorted).
// Epilogue zero-fills cls_out[count..100) -> no host-side memset needed.
// ---------------------------------------------------------------------------
__global__ __launch_bounds__(256) void k_nms(
    const float* __restrict__ top_s, const u32* __restrict__ top_idx,
    const float* __restrict__ boxes, float* __restrict__ cls_out) {
  const int c = blockIdx.x;
  const int tid = threadIdx.x, wave = tid >> 6, lane = tid & 63;
  __shared__ float4 sbox[TOPK];
  __shared__ float sarea[TOPK];
  __shared__ float sscore[TOPK];

  for (int i = tid; i < TOPK; i += 256) {
    u32 idx = top_idx[c * TOPK + i];
    if (idx >= N_DET) idx = 0;
    float4 b = ((const float4*)boxes)[idx];
    sbox[i] = b;
    sarea[i] = (b.z - b.x) * (b.w - b.y);
    sscore[i] = top_s[c * TOPK + i];
  }
  __syncthreads();

  if (wave == 0) {
    float4 kb0 = make_float4(0.f, 0.f, 0.f, 0.f), kb1 = kb0;
    float ka0 = 0.f, ka1 = 0.f;
    int count = 0;
    float sc_n = sscore[0];
    float4 b_n = sbox[0];
    float a_n = sarea[0];
    for (int i = 0; i < TOPK && count < 100; ++i) {
      float sc = sc_n;
      float4 bi = b_n;
      float ai = a_n;
      if (i + 1 < TOPK) {
        sc_n = sscore[i + 1];
        b_n = sbox[i + 1];
        a_n = sarea[i + 1];
      }
      if (!(sc > CONF)) break;
      bool sup0 = (lane < count) && iou_gt_half(kb0, ka0, bi, ai);
      bool sup1 = (lane + 64 < count) && iou_gt_half(kb1, ka1, bi, ai);
      u64 m = __ballot(sup0 || sup1);
      if (m == 0ull) {
        if (count < 64) {
          if (lane == count) { kb0 = bi; ka0 = ai; }
        } else {
          if (lane == count - 64) { kb1 = bi; ka1 = ai; }
        }
        if (lane == 0) cls_out[c * 128 + count] = sc;
        ++count;
      }
    }
    // zero-fill the unused tail (k_final reads exactly 100 per class)
    for (int i = count + lane; i < 100; i += 64)
      cls_out[c * 128 + i] = 0.0f;
  }
}

// ---------------------------------------------------------------------------
// Global top-100: hybrid two-level radix select, 1024 thr, 8 syncthreads.
// Fallback (nc>512, adversarial ties): multi-wave 8192 sort.
// ---------------------------------------------------------------------------
__global__ __launch_bounds__(1024) void k_final(
    const float* __restrict__ cls_out, float* __restrict__ out) {
  __shared__ u32 vals[8000];
  __shared__ u32 h1[8192];
  __shared__ u32 h2[16384];
  __shared__ u32 wsum[16];
  __shared__ u32 cands[512];
  __shared__ u32 sPref, sT2, sThr, scnt;
  const int t = threadIdx.x, wave = t >> 6, lane = t & 63;

  uint4 z4 = make_uint4(0u, 0u, 0u, 0u);
  for (int i = t; i < 2048; i += 1024) ((uint4*)h1)[i] = z4;
  for (int i = t; i < 4096; i += 1024) ((uint4*)h2)[i] = z4;
  if (t < 128) ((uint4*)cands)[t] = z4;
  if (t == 0) { sPref = 0; sT2 = 1; sThr = 0; scnt = 0; }
  __syncthreads();  // B1

  for (int i = t; i < 8000; i += 1024) {
    u32 b = __float_as_uint(cls_out[(i / 100) * 128 + (i % 100)]);
    vals[i] = b;
    u32 bin = b >> 17; if (bin > 8191u) bin = 8191u;
    atomicAdd(&h1[bin], 1u);
  }
  __syncthreads();  // B2

  {
    const u32 b0 = (u32)t * 8u;
    u32 loc[8]; u32 lsum = 0;
    #pragma unroll
    for (int k = 0; k < 8; ++k) { loc[k] = h1[b0 + k]; lsum += loc[k]; }
    u32 s = lsum;
    #pragma unroll
    for (int off = 1; off < 64; off <<= 1) {
      u32 v = __shfl_down(s, off, 64);
      if (lane + off < 64) s += v;
    }
    if (lane == 0) wsum[wave] = s;
    __syncthreads();  // B3
    u32 aboveW = 0;
    #pragma unroll
    for (int w = 0; w < 16; ++w) if (w > wave) aboveW += wsum[w];
    u32 above = aboveW + (s - lsum);
    if (above < 100u && above + lsum >= 100u) {
      u32 acc = above;
      #pragma unroll
      for (int k = 7; k >= 0; --k) {
        acc += loc[k];
        if (acc >= 100u) { sPref = b0 + (u32)k; sT2 = 100u - (acc - loc[k]); break; }
      }
    }
    __syncthreads();  // B4
  }
  const u32 pref = sPref, rt = sT2;

  for (int i = t; i < 8000; i += 1024) {
    u32 b = vals[i];
    u32 bin = b >> 17; if (bin > 8191u) bin = 8191u;
    if (bin == pref) atomicAdd(&h2[(b >> 3) & 0x3FFFu], 1u);
  }
  __syncthreads();  // B5

  {
    const u32 b0 = (u32)t * 16u;
    u32 loc[16]; u32 lsum = 0;
    #pragma unroll
    for (int k = 0; k < 16; ++k) { loc[k] = h2[b0 + k]; lsum += loc[k]; }
    u32 s = lsum;
    #pragma unroll
    for (int off = 1; off < 64; off <<= 1) {
      u32 v = __shfl_down(s, off, 64);
      if (lane + off < 64) s += v;
    }
    if (lane == 0) wsum[wave] = s;
    __syncthreads();  // B6
    u32 aboveW = 0;
    #pragma unroll
    for (int w = 0; w < 16; ++w) if (w > wave) aboveW += wsum[w];
    u32 above = aboveW + (s - lsum);
    if (above < rt && above + lsum >= rt) {
      u32 acc = above;
      #pragma unroll
      for (int k = 15; k >= 0; --k) {
        acc += loc[k];
        if (acc >= rt) { sThr = (pref << 17) | ((b0 + (u32)k) << 3); break; }
      }
    }
    __syncthreads();  // B7
  }
  const u32 thr = sThr;

  for (int i = t; i < 8000; i += 1024) {
    u32 v = vals[i];
    if (v >= thr) {
      u32 p = atomicAdd(&scnt, 1u);
      if (p < 512u) cands[p] = v;
    }
  }
  __syncthreads();  // B8
  const u32 nc = scnt;

  if (nc <= 512u) {
    if (wave == 0) {
      for (int k = 2; k <= 512; k <<= 1)
        for (int j = k >> 1; j > 0; j >>= 1) {
          for (int p = lane; p < 256; p += 64) {
            int i  = ((p & ~(j - 1)) << 1) | (p & (j - 1));
            int ix = i | j;
            bool up = (i & k) == 0;
            u32 a = cands[i], b = cands[ix];
            if (up ? (a < b) : (a > b)) { cands[i] = b; cands[ix] = a; }
          }
          __builtin_amdgcn_wave_barrier();
        }
      out[lane] = __uint_as_float(cands[lane]);
      if (lane < 36) out[lane + 64] = __uint_as_float(cands[lane + 64]);
    }
  } else {
    for (int i = t; i < 8192; i += 1024) h2[i] = (i < 8000) ? vals[i] : 0u;
    __syncthreads();
    for (int k = 2; k <= 8192; k <<= 1)
      for (int j = k >> 1; j > 0; j >>= 1) {
        for (int p = t; p < 4096; p += 1024) {
          int i  = ((p & ~(j - 1)) << 1) | (p & (j - 1));
          int ix = i | j;
          bool up = (i & k) == 0;
          u32 a = h2[i], b = h2[ix];
          if (up ? (a < b) : (a > b)) { h2[i] = b; h2[ix] = a; }
        }
        __syncthreads();
      }
    if (t < 100) out[t] = __uint_as_float(h2[t]);
  }
}

extern "C" void kernel_launch(void* const* d_in, const int* in_sizes, int n_in,
                              void* d_out, int out_size, void* d_ws, size_t ws_size,
                              hipStream_t stream) {
  const float* scores = (const float*)d_in[0];
  const float* boxes  = (const float*)d_in[1];
  float* out = (float*)d_out;
  char* ws = (char*)d_ws;

  u32* T16     = (u32*)(ws + OFF_T16);
  u32* prefA   = (u32*)(ws + OFF_PREFA);
  u32* tgtA    = (u32*)(ws + OFF_TGTA);
  u32* cnt     = (u32*)(ws + OFF_CNT);
  float* top_s = (float*)(ws + OFF_TOPS);
  u32* top_idx = (u32*)(ws + OFF_TOPI);
  float* cls_out = (float*)(ws + OFF_CLSOUT);
  u32* ghistA  = (u32*)(ws + OFF_GHA);
  u32* ghistB  = (u32*)(ws + OFF_GHB);
  u64* cand    = (u64*)(ws + OFF_CAND);
  u32* bcnt    = (u32*)(ws + OFF_BCNT);
  u32* bbase   = (u32*)(ws + OFF_BBASE);

  k_zero<<<30, 256, 0, stream>>>(ghistA);  // zeros ghistA+ghistB (contiguous)
  k_histA<<<NBLK, 256, 0, stream>>>(scores, ghistA);
  k_thrA<<<1, 256, 0, stream>>>(ghistA, prefA, tgtA);
  k_histB<<<NBLK, 256, 0, stream>>>(scores, prefA, ghistB);
  k_thrB<<<1, 256, 0, stream>>>(ghistB, prefA, tgtA, T16);
  k_count<<<NBLK, 256, 0, stream>>>(scores, T16, bcnt);
  k_offsets<<<1, 256, 0, stream>>>(bcnt, bbase, cnt);
  k_place<<<NBLK, 256, 0, stream>>>(scores, T16, bbase, cand);
  k_sort<<<N_CLS, 512, 0, stream>>>(cand, cnt, top_s, top_idx);
  k_nms<<<N_CLS, 256, 0, stream>>>(top_s, top_idx, boxes, cls_out);
  k_final<<<1, 1024, 0, stream>>>(cls_out, out);
}